// Round 4
// baseline (34853.864 us; speedup 1.0000x reference)
//
#include <hip/hip_runtime.h>
#include <hip/hip_bf16.h>
#include <hip/hip_cooperative_groups.h>

namespace cg = cooperative_groups;

typedef __bf16 bf16_t;
typedef __bf16 bf16x8 __attribute__((ext_vector_type(8)));
typedef float f32x4 __attribute__((ext_vector_type(4)));

#define TLEN 128
#define BATCHN 512
#define OBS 256
#define HID 1024
#define STATEDIM 1024
#define ROWS (TLEN * BATCHN)   // 65536
#define RKDT 0.25f

enum { EPI_F32 = 0, EPI_GI, EPI_TANH, EPI_K1, EPI_K2, EPI_K3, EPI_K4 };

__device__ __forceinline__ void gload_lds16(const bf16_t* g, bf16_t* l) {
  __builtin_amdgcn_global_load_lds(
      (const __attribute__((address_space(1))) void*)g,
      (__attribute__((address_space(3))) void*)l, 16, 0, 0);
}

__device__ __forceinline__ bf16_t f2bf(float x) { return (bf16_t)x; }

#define MF(a_, b_, c_) __builtin_amdgcn_mfma_f32_16x16x32_bf16(a_, b_, c_, 0, 0, 0)

// ============================================================================
// 256x256-tile 8-phase GEMM (T2 swizzle + T3/T4 counted vmcnt + T5 setprio).
// C = epi(A[M][K] @ Wt[N][K]^T + bias), A/Wt bf16 row-major, fp32 acc.
// 512 thr = 8 waves (2M x 4N); per-wave out 128x64 = acc[8][4] f32x4.
// LDS 128 KB: A/B each 2 bufs x 2 half-slots (16 KB = 128 rows x 64 k).
//   A slot lo = tile rows {0-63,128-191}, hi = {64-127,192-255}.
//   B slot lo = N-rows {wn*64+0..31}, hi = {wn*64+32..63}  (wn=0..3).
// Swizzle: 16B-chunk index ^= (row&7) — pre-swizzled global src, swz ds_read.
// K-tile tau (BK=64) phases: P1(rlo,clo) P2(rlo,chi) P3(rhi,clo) P4(rhi,chi).
//   A-lo dies after P2, B-lo after P3, A-hi/B-hi after P4 (quadrant order).
//   Stage: P1: A-hi,B-hi(tau+1); P3: A-lo(tau+2); P4: B-lo(tau+2).
//   Wait: one vmcnt(4) per K-tile at P4 (forces tile tau+1 complete; leaves
//   tau+2's lo-slots in flight) — never drains to 0 mid-loop.
// ============================================================================
template<int EPI>
__global__ __launch_bounds__(512, 2)
void gemm8(const bf16_t* __restrict__ A, const bf16_t* __restrict__ Wt,
           const float* __restrict__ bias, int M, int N, int K,
           float* __restrict__ outF, bf16_t* __restrict__ outB,
           float* __restrict__ Z, float* __restrict__ ZN,
           bf16_t* __restrict__ S2)
{
  __shared__ __align__(16) bf16_t lds[65536];   // 128 KB
  const int tid  = threadIdx.x;
  const int lane = tid & 63;
  const int wave = tid >> 6;
  const int wm = wave >> 2, wn = wave & 3;
  const int nbn = N >> 8;
  int bid = blockIdx.x;
  const int nwg = gridDim.x;
  if ((nwg & 7) == 0) {                 // bijective XCD swizzle (grid%8==0)
    const int cpx = nwg >> 3;
    bid = (bid & 7) * cpx + (bid >> 3);
  }
  const int bm = bid / nbn, bn = bid % nbn;
  const int m0 = bm << 8, n0 = bn << 8;
  const int nt = K >> 6;

  auto stA = [&](int tt, int s, int bb) {
    const int rl = tid >> 3;
    const int ks = (tid & 7) ^ (rl & 7);          // pre-swizzled global chunk
#pragma unroll
    for (int c = 0; c < 2; ++c) {
      const int r = c * 128 + s * 64 + rl;
      gload_lds16(A + (size_t)(m0 + r) * K + tt * 64 + ks * 8,
                  lds + bb * 16384 + s * 8192 + c * 4096 + tid * 8);
    }
  };
  auto stB = [&](int tt, int s, int bb) {
    const int rl = tid >> 3;
    const int ks = (tid & 7) ^ (rl & 7);
#pragma unroll
    for (int c = 0; c < 2; ++c) {
      const int lrb = c * 64 + rl;
      const int n = (lrb >> 5) * 64 + s * 32 + (lrb & 31);
      gload_lds16(Wt + (size_t)(n0 + n) * K + tt * 64 + ks * 8,
                  lds + 32768 + bb * 16384 + s * 8192 + c * 4096 + tid * 8);
    }
  };

  f32x4 acc[8][4] = {};

  // ---- prologue: tile0 (all 4 slots -> buf0) + tile1 lo-slots -> buf1 ----
  stA(0, 0, 0); stA(0, 1, 0); stB(0, 0, 0); stB(0, 1, 0);
  if (nt > 1) { stA(1, 0, 1); stB(1, 0, 1); }
  asm volatile("s_waitcnt vmcnt(4)" ::: "memory");   // tile0 landed
  __builtin_amdgcn_sched_barrier(0);
  __builtin_amdgcn_s_barrier();

#define PHASE(RQ, CQ, STAGECODE, WAITCODE) do {                                \
    const int kx0 = (lane >> 4) ^ (lane & 7);                                  \
    const int kx1 = (4 + (lane >> 4)) ^ (lane & 7);                            \
    const int abase = b * 16384 + (RQ) * 8192 + wm * 4096 + (lane & 15) * 64;  \
    const int bbase = 32768 + b * 16384 + (CQ) * 8192 + (wn >> 1) * 4096       \
                      + ((wn & 1) * 32 + (lane & 15)) * 64;                    \
    bf16x8 ar0k0 = *(const bf16x8*)(lds + abase +    0 + kx0 * 8);             \
    bf16x8 ar1k0 = *(const bf16x8*)(lds + abase + 1024 + kx0 * 8);             \
    bf16x8 ar2k0 = *(const bf16x8*)(lds + abase + 2048 + kx0 * 8);             \
    bf16x8 ar3k0 = *(const bf16x8*)(lds + abase + 3072 + kx0 * 8);             \
    bf16x8 ar0k1 = *(const bf16x8*)(lds + abase +    0 + kx1 * 8);             \
    bf16x8 ar1k1 = *(const bf16x8*)(lds + abase + 1024 + kx1 * 8);             \
    bf16x8 ar2k1 = *(const bf16x8*)(lds + abase + 2048 + kx1 * 8);             \
    bf16x8 ar3k1 = *(const bf16x8*)(lds + abase + 3072 + kx1 * 8);             \
    bf16x8 bc0k0 = *(const bf16x8*)(lds + bbase +    0 + kx0 * 8);             \
    bf16x8 bc1k0 = *(const bf16x8*)(lds + bbase + 1024 + kx0 * 8);             \
    bf16x8 bc0k1 = *(const bf16x8*)(lds + bbase +    0 + kx1 * 8);             \
    bf16x8 bc1k1 = *(const bf16x8*)(lds + bbase + 1024 + kx1 * 8);             \
    STAGECODE;                                                                 \
    __builtin_amdgcn_sched_barrier(0);                                         \
    __builtin_amdgcn_s_barrier();                                              \
    __builtin_amdgcn_s_setprio(1);                                             \
    acc[(RQ)*4+0][(CQ)*2+0] = MF(ar0k0, bc0k0, acc[(RQ)*4+0][(CQ)*2+0]);       \
    acc[(RQ)*4+0][(CQ)*2+1] = MF(ar0k0, bc1k0, acc[(RQ)*4+0][(CQ)*2+1]);       \
    acc[(RQ)*4+1][(CQ)*2+0] = MF(ar1k0, bc0k0, acc[(RQ)*4+1][(CQ)*2+0]);       \
    acc[(RQ)*4+1][(CQ)*2+1] = MF(ar1k0, bc1k0, acc[(RQ)*4+1][(CQ)*2+1]);       \
    acc[(RQ)*4+2][(CQ)*2+0] = MF(ar2k0, bc0k0, acc[(RQ)*4+2][(CQ)*2+0]);       \
    acc[(RQ)*4+2][(CQ)*2+1] = MF(ar2k0, bc1k0, acc[(RQ)*4+2][(CQ)*2+1]);       \
    acc[(RQ)*4+3][(CQ)*2+0] = MF(ar3k0, bc0k0, acc[(RQ)*4+3][(CQ)*2+0]);       \
    acc[(RQ)*4+3][(CQ)*2+1] = MF(ar3k0, bc1k0, acc[(RQ)*4+3][(CQ)*2+1]);       \
    acc[(RQ)*4+0][(CQ)*2+0] = MF(ar0k1, bc0k1, acc[(RQ)*4+0][(CQ)*2+0]);       \
    acc[(RQ)*4+0][(CQ)*2+1] = MF(ar0k1, bc1k1, acc[(RQ)*4+0][(CQ)*2+1]);       \
    acc[(RQ)*4+1][(CQ)*2+0] = MF(ar1k1, bc0k1, acc[(RQ)*4+1][(CQ)*2+0]);       \
    acc[(RQ)*4+1][(CQ)*2+1] = MF(ar1k1, bc1k1, acc[(RQ)*4+1][(CQ)*2+1]);       \
    acc[(RQ)*4+2][(CQ)*2+0] = MF(ar2k1, bc0k1, acc[(RQ)*4+2][(CQ)*2+0]);       \
    acc[(RQ)*4+2][(CQ)*2+1] = MF(ar2k1, bc1k1, acc[(RQ)*4+2][(CQ)*2+1]);       \
    acc[(RQ)*4+3][(CQ)*2+0] = MF(ar3k1, bc0k1, acc[(RQ)*4+3][(CQ)*2+0]);       \
    acc[(RQ)*4+3][(CQ)*2+1] = MF(ar3k1, bc1k1, acc[(RQ)*4+3][(CQ)*2+1]);       \
    __builtin_amdgcn_s_setprio(0);                                             \
    WAITCODE;                                                                  \
    __builtin_amdgcn_sched_barrier(0);                                         \
    __builtin_amdgcn_s_barrier();                                              \
  } while (0)

  for (int tau = 0; tau < nt; ++tau) {
    const int b = tau & 1;
    PHASE(0, 0, { if (tau + 1 < nt) { stA(tau + 1, 1, b ^ 1); stB(tau + 1, 1, b ^ 1); } }, {});
    PHASE(0, 1, {}, {});
    PHASE(1, 0, { if (tau + 2 < nt) stA(tau + 2, 0, b); }, {});
    PHASE(1, 1, { if (tau + 2 < nt) stB(tau + 2, 0, b); },
          { if (tau + 2 < nt) { asm volatile("s_waitcnt vmcnt(4)" ::: "memory"); }
            else              { asm volatile("s_waitcnt vmcnt(0)" ::: "memory"); } });
  }
#undef PHASE

  // ---- epilogue: C/D layout col=lane&15, row=(lane>>4)*4+reg ----
  const int rb0 = m0 + wm * 128 + ((lane >> 4) << 2);
  const int cb0 = n0 + wn * 64 + (lane & 15);
#pragma unroll
  for (int fj = 0; fj < 4; ++fj) {
    const int col = cb0 + fj * 16;
    float bv = 0.f;
    if constexpr (EPI != EPI_F32) bv = bias[col];
#pragma unroll
    for (int fi = 0; fi < 8; ++fi) {
#pragma unroll
      for (int q = 0; q < 4; ++q) {
        const int r = rb0 + fi * 16 + q;
        const size_t idx = (size_t)r * N + col;
        const float v = acc[fi][fj][q];
        if constexpr (EPI == EPI_F32) {
          outF[idx] = v;
        } else if constexpr (EPI == EPI_GI) {
          outF[idx] = v + bv;
        } else if constexpr (EPI == EPI_TANH) {
          outB[idx] = f2bf(tanhf(v + bv));
        } else {
          const float k = v + bv;          // N==1024 here
          const size_t si = (size_t)r * 2048 + col;
          float s;
          if constexpr (EPI == EPI_K1) {
            const float z = Z[idx];
            ZN[idx] = z + (RKDT / 6.f) * k;
            s = z + 0.5f * RKDT * k;
          } else if constexpr (EPI == EPI_K2) {
            const float z = Z[idx];
            ZN[idx] += (RKDT / 3.f) * k;
            s = z + 0.5f * RKDT * k;
          } else if constexpr (EPI == EPI_K3) {
            const float z = Z[idx];
            ZN[idx] += (RKDT / 3.f) * k;
            s = z + RKDT * k;
          } else {  // K4
            s = ZN[idx] + (RKDT / 6.f) * k;
            Z[idx] = s;
          }
          const bf16_t hi = f2bf(s);
          S2[si] = hi;
          S2[si + 1024] = f2bf(s - (float)hi);
        }
      }
    }
  }
}

// Persistent GRU (unchanged from round 3 — verified bit-identical).
__global__ __launch_bounds__(512)
void gru_persistent(const float* __restrict__ gi,   // [TS][512][3072] (bih incl)
                    const bf16_t* __restrict__ Whh, // [3072][1024] bf16
                    const float* __restrict__ bhh,  // [3072]
                    float* __restrict__ Hf,         // [512][1024] f32 persist
                    bf16_t* __restrict__ hb,        // [2][512][2048] split h
                    float* __restrict__ outp,       // d_out (f32)
                    int TS, int t0)
{
  __shared__ __align__(16) bf16_t Bs[48 * 1032];
  const int tid  = threadIdx.x;
  const int lane = tid & 63;
  const int w    = tid >> 6;
  const int rg   = blockIdx.x >> 6;
  const int jg   = blockIdx.x & 63;
  const int r0   = rg << 7;
  const int j0   = jg << 4;

  for (int it = tid; it < 48 * 128; it += 512) {
    const int rr = it >> 7;
    const int co = (it & 127) << 3;
    const int g = rr >> 4, c = rr & 15;
    *(bf16x8*)&Bs[rr * 1032 + co] =
        *(const bf16x8*)&Whh[(size_t)(g * 1024 + j0 + c) * 1024 + co];
  }

  const int myj = j0 + (lane & 15);
  const float bh_r = bhh[myj], bh_z = bhh[1024 + myj], bh_n = bhh[2048 + myj];
  const int rbase = r0 + w * 16 + ((lane >> 4) << 2);

  float h[4];
#pragma unroll
  for (int q = 0; q < 4; ++q) h[q] = Hf[(size_t)(rbase + q) * 1024 + myj];

  __syncthreads();
  cg::grid_group grid = cg::this_grid();

  const int arow = r0 + w * 16 + (lane & 15);
  const int akoff = (lane >> 4) << 3;

  for (int t = t0; t < t0 + TS; ++t) {
    const bf16_t* ap = hb + (size_t)(t & 1) * 512 * 2048 +
                       (size_t)arow * 2048 + akoff;
    f32x4 a0 = {}, a1 = {}, a2 = {};
    const bf16_t* bp0 = &Bs[(0  + (lane & 15)) * 1032 + akoff];
    const bf16_t* bp1 = &Bs[(16 + (lane & 15)) * 1032 + akoff];
    const bf16_t* bp2 = &Bs[(32 + (lane & 15)) * 1032 + akoff];
#pragma unroll 8
    for (int kc = 0; kc < 64; ++kc) {
      const bf16x8 af = *(const bf16x8*)(ap + kc * 32);
      const int kl = (kc * 32) & 1023;
      a0 = MF(af, *(const bf16x8*)(bp0 + kl), a0);
      a1 = MF(af, *(const bf16x8*)(bp1 + kl), a1);
      a2 = MF(af, *(const bf16x8*)(bp2 + kl), a2);
    }
    const float* gir = gi + (size_t)(t - t0) * 512 * 3072;
    bf16_t* hbw = hb + (size_t)((t + 1) & 1) * 512 * 2048;
#pragma unroll
    for (int q = 0; q < 4; ++q) {
      const size_t rr = (size_t)(rbase + q);
      const float ir = gir[rr * 3072 + myj];
      const float iz = gir[rr * 3072 + 1024 + myj];
      const float in = gir[rr * 3072 + 2048 + myj];
      const float rg_ = 1.f / (1.f + expf(-(ir + a0[q] + bh_r)));
      const float zg  = 1.f / (1.f + expf(-(iz + a1[q] + bh_z)));
      const float n   = tanhf(in + rg_ * (a2[q] + bh_n));
      h[q] = (1.f - zg) * n + zg * h[q];
      const bf16_t hi = f2bf(h[q]);
      hbw[rr * 2048 + myj] = hi;
      hbw[rr * 2048 + 1024 + myj] = f2bf(h[q] - (float)hi);
    }
    grid.sync();
  }

#pragma unroll
  for (int q = 0; q < 4; ++q) {
    const int r = rbase + q;
    Hf[(size_t)r * 1024 + myj] = h[q];
    if (myj < 512) outp[(size_t)r * 512 + myj] = h[q];
    else           outp[262144 + (size_t)r * 512 + (myj - 512)] = h[q];
  }
}

// per-row LayerNorm(+bias) + LeakyReLU(0.1), row width 1024.
template<bool SPLIT>
__global__ __launch_bounds__(256)
void ln_leaky(const float* __restrict__ pre, const float* __restrict__ b,
              const float* __restrict__ g, const float* __restrict__ bet,
              bf16_t* __restrict__ outB, float* __restrict__ zf)
{
  const int row = blockIdx.x;
  const int tid = threadIdx.x;
  const float* p = pre + (size_t)row * 1024;
  float v[4];
  float s = 0.f, s2 = 0.f;
#pragma unroll
  for (int i = 0; i < 4; ++i) {
    const int c = tid + i * 256;
    v[i] = p[c] + b[c];
    s += v[i]; s2 += v[i] * v[i];
  }
#pragma unroll
  for (int o = 32; o; o >>= 1) { s += __shfl_down(s, o); s2 += __shfl_down(s2, o); }
  __shared__ float rs[4], rs2[4];
  if ((tid & 63) == 0) { rs[tid >> 6] = s; rs2[tid >> 6] = s2; }
  __syncthreads();
  s = rs[0] + rs[1] + rs[2] + rs[3];
  s2 = rs2[0] + rs2[1] + rs2[2] + rs2[3];
  const float mu = s * (1.f / 1024.f);
  const float var = s2 * (1.f / 1024.f) - mu * mu;
  const float rstd = rsqrtf(var + 1e-5f);
#pragma unroll
  for (int i = 0; i < 4; ++i) {
    const int c = tid + i * 256;
    float h = (v[i] - mu) * rstd * g[c] + bet[c];
    h = h >= 0.f ? h : 0.1f * h;
    if constexpr (SPLIT) {
      const bf16_t hi = f2bf(h);
      outB[(size_t)row * 2048 + c] = hi;
      outB[(size_t)row * 2048 + 1024 + c] = f2bf(h - (float)hi);
      zf[(size_t)row * 1024 + c] = h;
    } else {
      outB[(size_t)row * 1024 + c] = f2bf(h);
    }
  }
}

__global__ __launch_bounds__(256)
void transpose_bf16(const float* __restrict__ in, bf16_t* __restrict__ out, int R, int C)
{
  __shared__ float t[32][33];
  const int c0 = blockIdx.x * 32, r0 = blockIdx.y * 32;
  const int tx = threadIdx.x & 31, ty = threadIdx.x >> 5;
#pragma unroll
  for (int i = 0; i < 32; i += 8)
    t[ty + i][tx] = in[(size_t)(r0 + ty + i) * C + c0 + tx];
  __syncthreads();
#pragma unroll
  for (int i = 0; i < 32; i += 8)
    out[(size_t)(c0 + ty + i) * R + r0 + tx] = f2bf(t[tx][ty + i]);
}

__global__ __launch_bounds__(256)
void f2b_kernel(const float* __restrict__ in, bf16_t* __restrict__ out, int n)
{
  const int i = blockIdx.x * 256 + threadIdx.x;
  if (i < n) out[i] = f2bf(in[i]);
}

__global__ __launch_bounds__(256)
void dup2_kernel(const bf16_t* __restrict__ in, bf16_t* __restrict__ out, int N, int K)
{
  const int idx = blockIdx.x * 256 + threadIdx.x;
  if (idx >= N * 2 * K) return;
  const int n = idx / (2 * K);
  const int kk = idx - n * 2 * K;
  const int k = kk < K ? kk : kk - K;
  out[idx] = in[(size_t)n * K + k];
}

__global__ void sentinel_kernel(float* out, float code) {
  if (threadIdx.x == 0 && blockIdx.x == 0) out[0] = code;
}

extern "C" void kernel_launch(void* const* d_in, const int* in_sizes, int n_in,
                              void* d_out, int out_size, void* d_ws, size_t ws_size,
                              hipStream_t stream)
{
  const float* xs    = (const float*)d_in[0];
  const float* obs_W = (const float*)d_in[1];
  const float* obs_b = (const float*)d_in[2];
  const float* obs_g = (const float*)d_in[3];
  const float* obs_be= (const float*)d_in[4];
  const float* lat_W = (const float*)d_in[5];
  const float* lat_b = (const float*)d_in[6];
  const float* lat_g = (const float*)d_in[7];
  const float* lat_be= (const float*)d_in[8];
  const float* W0    = (const float*)d_in[9];
  const float* b0    = (const float*)d_in[10];
  const float* W1    = (const float*)d_in[11];
  const float* b1    = (const float*)d_in[12];
  const float* W2    = (const float*)d_in[13];
  const float* b2    = (const float*)d_in[14];
  const float* Wih   = (const float*)d_in[15];
  const float* Whh   = (const float*)d_in[16];
  const float* bih   = (const float*)d_in[17];
  const float* bhh   = (const float*)d_in[18];

  char* ws = (char*)d_ws;
  size_t off = 0;
  auto alloc = [&](size_t bytes) { char* p = ws + off; off += bytes; return p; };

  // ---- static region (~76 MB) ----
  bf16_t* OBSWT = (bf16_t*)alloc((size_t)HID * OBS * 2);
  bf16_t* LATWT = (bf16_t*)alloc((size_t)STATEDIM * HID * 2);
  bf16_t* W0T2  = (bf16_t*)alloc((size_t)HID * 2048 * 2);
  bf16_t* W1T   = (bf16_t*)alloc((size_t)HID * HID * 2);
  bf16_t* W2T   = (bf16_t*)alloc((size_t)STATEDIM * HID * 2);
  bf16_t* WIH2  = (bf16_t*)alloc((size_t)3072 * 2048 * 2);
  bf16_t* WHHB  = (bf16_t*)alloc((size_t)3072 * 1024 * 2);
  float*  Hf    = (float*)alloc((size_t)512 * 1024 * 4);
  bf16_t* HB2   = (bf16_t*)alloc((size_t)2 * 512 * 2048 * 2);
  bf16_t* W0T   = (bf16_t*)alloc((size_t)HID * HID * 2);       // temp
  bf16_t* WIHB  = (bf16_t*)alloc((size_t)3072 * 1024 * 2);     // temp
  bf16_t* XSB   = (bf16_t*)alloc((size_t)ROWS * OBS * 2);      // bf16 input, all rows
  const size_t staticEnd = off;

  // ---- chunking: per-row arena A1(4096)+A2(4096)+H1(2048)+H2(2048)+S2(4096)
  //      = 16384 B; GI f32 (12288 B/row) overlaps A1+A2+H1+H2.
  int nc = -1;
  const int ncs[8] = {1, 2, 4, 8, 16, 32, 64, 128};
  for (int i = 0; i < 8; ++i) {
    const size_t R = (size_t)ROWS / ncs[i];
    if (staticEnd + R * 16384 <= ws_size) { nc = ncs[i]; break; }
  }
  if (nc < 0) {
    sentinel_kernel<<<1, 1, 0, stream>>>((float*)d_out,
                                         -(1000000.0f + (float)(ws_size >> 20)));
    return;
  }
  const int R = ROWS / nc;
  char* arena = ws + staticEnd;
  float*  A1f  = (float*)(arena);                       // pre-LN / ZN
  float*  A2f  = (float*)(arena + (size_t)R * 4096);    // z fp32
  bf16_t* H1b  = (bf16_t*)(arena + (size_t)R * 8192);
  bf16_t* H2b  = (bf16_t*)(arena + (size_t)R * 10240);
  bf16_t* S2b  = (bf16_t*)(arena + (size_t)R * 12288);  // split z / stage input
  float*  GIf  = (float*)(arena);                       // gi f32 overlaps A1..H2

  auto gemm = [&](int epi, const bf16_t* A, const bf16_t* Wt, const float* bias,
                  int M, int N, int K, float* oF, bf16_t* oB) {
    dim3 g((M / 256) * (N / 256)), b(512);
    switch (epi) {
      case EPI_F32:  gemm8<EPI_F32><<<g, b, 0, stream>>>(A, Wt, bias, M, N, K, oF, oB, A2f, A1f, S2b); break;
      case EPI_GI:   gemm8<EPI_GI><<<g, b, 0, stream>>>(A, Wt, bias, M, N, K, oF, oB, A2f, A1f, S2b); break;
      case EPI_TANH: gemm8<EPI_TANH><<<g, b, 0, stream>>>(A, Wt, bias, M, N, K, oF, oB, A2f, A1f, S2b); break;
      case EPI_K1:   gemm8<EPI_K1><<<g, b, 0, stream>>>(A, Wt, bias, M, N, K, oF, oB, A2f, A1f, S2b); break;
      case EPI_K2:   gemm8<EPI_K2><<<g, b, 0, stream>>>(A, Wt, bias, M, N, K, oF, oB, A2f, A1f, S2b); break;
      case EPI_K3:   gemm8<EPI_K3><<<g, b, 0, stream>>>(A, Wt, bias, M, N, K, oF, oB, A2f, A1f, S2b); break;
      case EPI_K4:   gemm8<EPI_K4><<<g, b, 0, stream>>>(A, Wt, bias, M, N, K, oF, oB, A2f, A1f, S2b); break;
    }
  };

  // ---- weight prep ----
  transpose_bf16<<<dim3(HID / 32, OBS / 32), 256, 0, stream>>>(obs_W, OBSWT, OBS, HID);
  transpose_bf16<<<dim3(STATEDIM / 32, HID / 32), 256, 0, stream>>>(lat_W, LATWT, HID, STATEDIM);
  transpose_bf16<<<dim3(HID / 32, STATEDIM / 32), 256, 0, stream>>>(W0, W0T, STATEDIM, HID);
  dup2_kernel<<<(HID * 2048) / 256, 256, 0, stream>>>(W0T, W0T2, HID, 1024);
  transpose_bf16<<<dim3(HID / 32, HID / 32), 256, 0, stream>>>(W1, W1T, HID, HID);
  transpose_bf16<<<dim3(STATEDIM / 32, HID / 32), 256, 0, stream>>>(W2, W2T, HID, STATEDIM);
  f2b_kernel<<<(3072 * 1024) / 256, 256, 0, stream>>>(Wih, WIHB, 3072 * 1024);
  dup2_kernel<<<(3072 * 2048) / 256, 256, 0, stream>>>(WIHB, WIH2, 3072, 1024);
  f2b_kernel<<<(3072 * 1024) / 256, 256, 0, stream>>>(Whh, WHHB, 3072 * 1024);
  f2b_kernel<<<(ROWS * OBS) / 256, 256, 0, stream>>>(xs, XSB, ROWS * OBS);

  hipMemsetAsync(Hf, 0, (size_t)512 * 1024 * 4, stream);
  hipMemsetAsync(HB2, 0, (size_t)2 * 512 * 2048 * 2, stream);
  const int TS = R / BATCHN;

  for (int c = 0; c < nc; ++c) {
    // encoder MLPs
    gemm(EPI_F32, XSB + (size_t)c * R * OBS, OBSWT, nullptr, R, HID, OBS, A1f, nullptr);
    ln_leaky<false><<<R, 256, 0, stream>>>(A1f, obs_b, obs_g, obs_be, H1b, nullptr);
    gemm(EPI_F32, H1b, LATWT, nullptr, R, STATEDIM, HID, A1f, nullptr);
    ln_leaky<true><<<R, 256, 0, stream>>>(A1f, lat_b, lat_g, lat_be, S2b, A2f);

    // RK4: 4 steps x 4 stages x 3 GEMMs
    for (int step = 0; step < 4; ++step) {
      for (int stg = 0; stg < 4; ++stg) {
        gemm(EPI_TANH, S2b, W0T2, b0, R, HID, 2048, nullptr, H1b);
        gemm(EPI_TANH, H1b, W1T, b1, R, HID, HID, nullptr, H2b);
        gemm(EPI_K1 + stg, H2b, W2T, b2, R, STATEDIM, HID, nullptr, nullptr);
      }
    }

    // gi = z_final @ Wih^T + bih (split-z, f32 out) — overwrites dead A1..H2
    gemm(EPI_GI, S2b, WIH2, bih, R, 3072, 2048, GIf, nullptr);

    // persistent GRU over this chunk's timesteps
    {
      const float* giArg = GIf;
      const bf16_t* whhArg = WHHB;
      const float* bhhArg = bhh;
      float* hfArg = Hf;
      bf16_t* hbArg = HB2;
      float* outArg = (float*)d_out;
      int tsArg = TS;
      int t0Arg = c * TS;
      void* args[] = { (void*)&giArg, (void*)&whhArg, (void*)&bhhArg,
                       (void*)&hfArg, (void*)&hbArg, (void*)&outArg,
                       (void*)&tsArg, (void*)&t0Arg };
      hipLaunchCooperativeKernel((const void*)gru_persistent,
                                 dim3(256), dim3(512), args, 0, stream);
    }
  }
}

// Round 5
// 32141.028 us; speedup vs baseline: 1.0844x; 1.0844x over previous
//
#include <hip/hip_runtime.h>
#include <hip/hip_bf16.h>
#include <hip/hip_cooperative_groups.h>

namespace cg = cooperative_groups;

typedef __bf16 bf16_t;
typedef __bf16 bf16x8 __attribute__((ext_vector_type(8)));
typedef float f32x4 __attribute__((ext_vector_type(4)));

#define TLEN 128
#define BATCHN 512
#define OBS 256
#define HID 1024
#define STATEDIM 1024
#define ROWS (TLEN * BATCHN)   // 65536
#define RKDT 0.25f

enum { EPI_F32 = 0, EPI_GI, EPI_TANH, EPI_K1, EPI_K2, EPI_K3, EPI_K4 };

__device__ __forceinline__ void gload_lds16(const bf16_t* g, bf16_t* l) {
  __builtin_amdgcn_global_load_lds(
      (const __attribute__((address_space(1))) void*)g,
      (__attribute__((address_space(3))) void*)l, 16, 0, 0);
}

__device__ __forceinline__ bf16_t f2bf(float x) { return (bf16_t)x; }

#define MF(a_, b_, c_) __builtin_amdgcn_mfma_f32_16x16x32_bf16(a_, b_, c_, 0, 0, 0)

// ============================================================================
// 256x256-tile 8-phase GEMM, register-cached fragments (24 ds_read_b128 per
// K-tile per wave — m201 ratio; r4's port did 48 and was LDS-read-bound).
// C = epi(A[M][K] @ Wt[N][K]^T + bias), A/Wt bf16 row-major, fp32 acc.
// 512 thr = 8 waves (2M x 4N); per-wave out 128x64 = acc[8][4] f32x4.
// LDS 128 KB: A/B x 2 bufs x 2 slots (slot = 8K elems = 128 rows x 64 k).
// Swizzle: 16B-chunk ^= (row&7), pre-swizzled global src + swizzled read.
// Phases per K-tile tau:
//   P1 (RQ0,CQ0): read A-lo(8)+B-lo(4); stage A-hi(tau+1)
//   P2 (RQ0,CQ1): read B-hi(4), reuse A-lo; stage B-hi(tau+1)
//   P3 (RQ1,CQ0): read A-hi(8), reuse B-lo; stage A-lo(tau+2)
//   P4 (RQ1,CQ1): no reads, reuse A-hi+B-hi; stage B-lo(tau+2);
//                 vmcnt(4) (=> tile tau+1 resident, lo(tau+2) in flight)
// ============================================================================
template<int EPI>
__global__ __launch_bounds__(512, 2)
void gemm8(const bf16_t* __restrict__ A, const bf16_t* __restrict__ Wt,
           const float* __restrict__ bias, int M, int N, int K,
           float* __restrict__ outF, bf16_t* __restrict__ outB,
           float* __restrict__ Z, float* __restrict__ ZN,
           bf16_t* __restrict__ S2)
{
  __shared__ __align__(16) bf16_t lds[65536];   // 128 KB
  const int tid  = threadIdx.x;
  const int lane = tid & 63;
  const int wave = tid >> 6;
  const int wm = wave >> 2, wn = wave & 3;
  const int nbn = N >> 8;
  int bid = blockIdx.x;
  const int nwg = gridDim.x;
  if ((nwg & 7) == 0) {                 // bijective XCD swizzle (grid%8==0)
    const int cpx = nwg >> 3;
    bid = (bid & 7) * cpx + (bid >> 3);
  }
  const int bm = bid / nbn, bn = bid % nbn;
  const int m0 = bm << 8, n0 = bn << 8;
  const int nt = K >> 6;

  auto stA = [&](int tt, int s, int bb) {
    const int rl = tid >> 3;
    const int ks = (tid & 7) ^ (rl & 7);          // pre-swizzled global chunk
#pragma unroll
    for (int c = 0; c < 2; ++c) {
      const int r = c * 128 + s * 64 + rl;
      gload_lds16(A + (size_t)(m0 + r) * K + tt * 64 + ks * 8,
                  lds + bb * 16384 + s * 8192 + c * 4096 + tid * 8);
    }
  };
  auto stB = [&](int tt, int s, int bb) {
    const int rl = tid >> 3;
    const int ks = (tid & 7) ^ (rl & 7);
#pragma unroll
    for (int c = 0; c < 2; ++c) {
      const int lrb = c * 64 + rl;
      const int n = (lrb >> 5) * 64 + s * 32 + (lrb & 31);
      gload_lds16(Wt + (size_t)(n0 + n) * K + tt * 64 + ks * 8,
                  lds + 32768 + bb * 16384 + s * 8192 + c * 4096 + tid * 8);
    }
  };

  f32x4 acc[8][4] = {};

  // read-address constants (lane-uniform within wave role)
  const int kx0 = (lane >> 4) ^ (lane & 7);
  const int kx1 = (4 + (lane >> 4)) ^ (lane & 7);
  const int aoff = (lane & 15) * 64;
  const int boff = ((wn & 1) * 32 + (lane & 15)) * 64;

  bf16x8 a0k0, a1k0, a2k0, a3k0, a0k1, a1k1, a2k1, a3k1;
  bf16x8 bl0k0, bl1k0, bl0k1, bl1k1, bh0k0, bh1k0, bh0k1, bh1k1;

#define LDA(RQ) do {                                                           \
    const bf16_t* ab_ = lds + b * 16384 + (RQ) * 8192 + wm * 4096 + aoff;      \
    a0k0 = *(const bf16x8*)(ab_ +    0 + kx0 * 8);                             \
    a1k0 = *(const bf16x8*)(ab_ + 1024 + kx0 * 8);                             \
    a2k0 = *(const bf16x8*)(ab_ + 2048 + kx0 * 8);                             \
    a3k0 = *(const bf16x8*)(ab_ + 3072 + kx0 * 8);                             \
    a0k1 = *(const bf16x8*)(ab_ +    0 + kx1 * 8);                             \
    a1k1 = *(const bf16x8*)(ab_ + 1024 + kx1 * 8);                             \
    a2k1 = *(const bf16x8*)(ab_ + 2048 + kx1 * 8);                             \
    a3k1 = *(const bf16x8*)(ab_ + 3072 + kx1 * 8);                             \
  } while (0)
#define LDB(CQ, r0k0, r1k0, r0k1, r1k1) do {                                   \
    const bf16_t* bb_ = lds + 32768 + b * 16384 + (CQ) * 8192                  \
                        + (wn >> 1) * 4096 + boff;                             \
    r0k0 = *(const bf16x8*)(bb_ +    0 + kx0 * 8);                             \
    r1k0 = *(const bf16x8*)(bb_ + 1024 + kx0 * 8);                             \
    r0k1 = *(const bf16x8*)(bb_ +    0 + kx1 * 8);                             \
    r1k1 = *(const bf16x8*)(bb_ + 1024 + kx1 * 8);                             \
  } while (0)
#define CLUST(BF, c0k0, c1k0, c0k1, c1k1, CQ) do {                             \
    acc[(BF)+0][(CQ)*2+0] = MF(a0k0, c0k0, acc[(BF)+0][(CQ)*2+0]);             \
    acc[(BF)+0][(CQ)*2+1] = MF(a0k0, c1k0, acc[(BF)+0][(CQ)*2+1]);             \
    acc[(BF)+1][(CQ)*2+0] = MF(a1k0, c0k0, acc[(BF)+1][(CQ)*2+0]);             \
    acc[(BF)+1][(CQ)*2+1] = MF(a1k0, c1k0, acc[(BF)+1][(CQ)*2+1]);             \
    acc[(BF)+2][(CQ)*2+0] = MF(a2k0, c0k0, acc[(BF)+2][(CQ)*2+0]);             \
    acc[(BF)+2][(CQ)*2+1] = MF(a2k0, c1k0, acc[(BF)+2][(CQ)*2+1]);             \
    acc[(BF)+3][(CQ)*2+0] = MF(a3k0, c0k0, acc[(BF)+3][(CQ)*2+0]);             \
    acc[(BF)+3][(CQ)*2+1] = MF(a3k0, c1k0, acc[(BF)+3][(CQ)*2+1]);             \
    acc[(BF)+0][(CQ)*2+0] = MF(a0k1, c0k1, acc[(BF)+0][(CQ)*2+0]);             \
    acc[(BF)+0][(CQ)*2+1] = MF(a0k1, c1k1, acc[(BF)+0][(CQ)*2+1]);             \
    acc[(BF)+1][(CQ)*2+0] = MF(a1k1, c0k1, acc[(BF)+1][(CQ)*2+0]);             \
    acc[(BF)+1][(CQ)*2+1] = MF(a1k1, c1k1, acc[(BF)+1][(CQ)*2+1]);             \
    acc[(BF)+2][(CQ)*2+0] = MF(a2k1, c0k1, acc[(BF)+2][(CQ)*2+0]);             \
    acc[(BF)+2][(CQ)*2+1] = MF(a2k1, c1k1, acc[(BF)+2][(CQ)*2+1]);             \
    acc[(BF)+3][(CQ)*2+0] = MF(a3k1, c0k1, acc[(BF)+3][(CQ)*2+0]);             \
    acc[(BF)+3][(CQ)*2+1] = MF(a3k1, c1k1, acc[(BF)+3][(CQ)*2+1]);             \
  } while (0)

  // ---- prologue: tile0 all slots -> buf0; tile1 lo-slots -> buf1 ----
  stA(0, 0, 0); stA(0, 1, 0); stB(0, 0, 0); stB(0, 1, 0);
  if (nt > 1) { stA(1, 0, 1); stB(1, 0, 1); }
  asm volatile("s_waitcnt vmcnt(4)" ::: "memory");   // tile0 landed
  __builtin_amdgcn_sched_barrier(0);
  __builtin_amdgcn_s_barrier();

  for (int tau = 0; tau < nt; ++tau) {
    const int b = tau & 1;
    // ---- P1: RQ0,CQ0 ----
    LDA(0);
    LDB(0, bl0k0, bl1k0, bl0k1, bl1k1);
    if (tau + 1 < nt) stA(tau + 1, 1, b ^ 1);
    __builtin_amdgcn_sched_barrier(0);
    __builtin_amdgcn_s_barrier();
    __builtin_amdgcn_s_setprio(1);
    CLUST(0, bl0k0, bl1k0, bl0k1, bl1k1, 0);
    __builtin_amdgcn_s_setprio(0);
    __builtin_amdgcn_sched_barrier(0);
    __builtin_amdgcn_s_barrier();
    // ---- P2: RQ0,CQ1 (reuse A-lo) ----
    LDB(1, bh0k0, bh1k0, bh0k1, bh1k1);
    if (tau + 1 < nt) stB(tau + 1, 1, b ^ 1);
    __builtin_amdgcn_sched_barrier(0);
    __builtin_amdgcn_s_barrier();
    __builtin_amdgcn_s_setprio(1);
    CLUST(0, bh0k0, bh1k0, bh0k1, bh1k1, 1);
    __builtin_amdgcn_s_setprio(0);
    __builtin_amdgcn_sched_barrier(0);
    __builtin_amdgcn_s_barrier();
    // ---- P3: RQ1,CQ0 (reuse B-lo) ----
    LDA(1);
    if (tau + 2 < nt) stA(tau + 2, 0, b);
    __builtin_amdgcn_sched_barrier(0);
    __builtin_amdgcn_s_barrier();
    __builtin_amdgcn_s_setprio(1);
    CLUST(4, bl0k0, bl1k0, bl0k1, bl1k1, 0);
    __builtin_amdgcn_s_setprio(0);
    __builtin_amdgcn_sched_barrier(0);
    __builtin_amdgcn_s_barrier();
    // ---- P4: RQ1,CQ1 (reuse A-hi + B-hi) ----
    if (tau + 2 < nt) stB(tau + 2, 0, b);
    __builtin_amdgcn_sched_barrier(0);
    __builtin_amdgcn_s_barrier();
    __builtin_amdgcn_s_setprio(1);
    CLUST(4, bh0k0, bh1k0, bh0k1, bh1k1, 1);
    __builtin_amdgcn_s_setprio(0);
    if (tau + 2 < nt) { asm volatile("s_waitcnt vmcnt(4)" ::: "memory"); }
    else              { asm volatile("s_waitcnt vmcnt(0)" ::: "memory"); }
    __builtin_amdgcn_sched_barrier(0);
    __builtin_amdgcn_s_barrier();
  }
#undef LDA
#undef LDB
#undef CLUST

  // ---- epilogue: C/D layout col=lane&15, row=(lane>>4)*4+reg ----
  const int rb0 = m0 + wm * 128 + ((lane >> 4) << 2);
  const int cb0 = n0 + wn * 64 + (lane & 15);
#pragma unroll
  for (int fj = 0; fj < 4; ++fj) {
    const int col = cb0 + fj * 16;
    float bv = 0.f;
    if constexpr (EPI != EPI_F32) bv = bias[col];
#pragma unroll
    for (int fi = 0; fi < 8; ++fi) {
#pragma unroll
      for (int q = 0; q < 4; ++q) {
        const int r = rb0 + fi * 16 + q;
        const size_t idx = (size_t)r * N + col;
        const float v = acc[fi][fj][q];
        if constexpr (EPI == EPI_F32) {
          outF[idx] = v;
        } else if constexpr (EPI == EPI_GI) {
          outF[idx] = v + bv;
        } else if constexpr (EPI == EPI_TANH) {
          outB[idx] = f2bf(tanhf(v + bv));
        } else {
          const float k = v + bv;          // N==1024 here
          const size_t si = (size_t)r * 2048 + col;
          float s;
          if constexpr (EPI == EPI_K1) {
            const float z = Z[idx];
            ZN[idx] = z + (RKDT / 6.f) * k;
            s = z + 0.5f * RKDT * k;
          } else if constexpr (EPI == EPI_K2) {
            const float z = Z[idx];
            ZN[idx] += (RKDT / 3.f) * k;
            s = z + 0.5f * RKDT * k;
          } else if constexpr (EPI == EPI_K3) {
            const float z = Z[idx];
            ZN[idx] += (RKDT / 3.f) * k;
            s = z + RKDT * k;
          } else {  // K4
            s = ZN[idx] + (RKDT / 6.f) * k;
            Z[idx] = s;
          }
          const bf16_t hi = f2bf(s);
          S2[si] = hi;
          S2[si + 1024] = f2bf(s - (float)hi);
        }
      }
    }
  }
}

// Persistent GRU (unchanged — verified bit-identical).
__global__ __launch_bounds__(512)
void gru_persistent(const float* __restrict__ gi,   // [TS][512][3072] (bih incl)
                    const bf16_t* __restrict__ Whh, // [3072][1024] bf16
                    const float* __restrict__ bhh,  // [3072]
                    float* __restrict__ Hf,         // [512][1024] f32 persist
                    bf16_t* __restrict__ hb,        // [2][512][2048] split h
                    float* __restrict__ outp,       // d_out (f32)
                    int TS, int t0)
{
  __shared__ __align__(16) bf16_t Bs[48 * 1032];
  const int tid  = threadIdx.x;
  const int lane = tid & 63;
  const int w    = tid >> 6;
  const int rg   = blockIdx.x >> 6;
  const int jg   = blockIdx.x & 63;
  const int r0   = rg << 7;
  const int j0   = jg << 4;

  for (int it = tid; it < 48 * 128; it += 512) {
    const int rr = it >> 7;
    const int co = (it & 127) << 3;
    const int g = rr >> 4, c = rr & 15;
    *(bf16x8*)&Bs[rr * 1032 + co] =
        *(const bf16x8*)&Whh[(size_t)(g * 1024 + j0 + c) * 1024 + co];
  }

  const int myj = j0 + (lane & 15);
  const float bh_r = bhh[myj], bh_z = bhh[1024 + myj], bh_n = bhh[2048 + myj];
  const int rbase = r0 + w * 16 + ((lane >> 4) << 2);

  float h[4];
#pragma unroll
  for (int q = 0; q < 4; ++q) h[q] = Hf[(size_t)(rbase + q) * 1024 + myj];

  __syncthreads();
  cg::grid_group grid = cg::this_grid();

  const int arow = r0 + w * 16 + (lane & 15);
  const int akoff = (lane >> 4) << 3;

  for (int t = t0; t < t0 + TS; ++t) {
    const bf16_t* ap = hb + (size_t)(t & 1) * 512 * 2048 +
                       (size_t)arow * 2048 + akoff;
    f32x4 a0 = {}, a1 = {}, a2 = {};
    const bf16_t* bp0 = &Bs[(0  + (lane & 15)) * 1032 + akoff];
    const bf16_t* bp1 = &Bs[(16 + (lane & 15)) * 1032 + akoff];
    const bf16_t* bp2 = &Bs[(32 + (lane & 15)) * 1032 + akoff];
#pragma unroll 8
    for (int kc = 0; kc < 64; ++kc) {
      const bf16x8 af = *(const bf16x8*)(ap + kc * 32);
      const int kl = (kc * 32) & 1023;
      a0 = MF(af, *(const bf16x8*)(bp0 + kl), a0);
      a1 = MF(af, *(const bf16x8*)(bp1 + kl), a1);
      a2 = MF(af, *(const bf16x8*)(bp2 + kl), a2);
    }
    const float* gir = gi + (size_t)(t - t0) * 512 * 3072;
    bf16_t* hbw = hb + (size_t)((t + 1) & 1) * 512 * 2048;
#pragma unroll
    for (int q = 0; q < 4; ++q) {
      const size_t rr = (size_t)(rbase + q);
      const float ir = gir[rr * 3072 + myj];
      const float iz = gir[rr * 3072 + 1024 + myj];
      const float in = gir[rr * 3072 + 2048 + myj];
      const float rg_ = 1.f / (1.f + expf(-(ir + a0[q] + bh_r)));
      const float zg  = 1.f / (1.f + expf(-(iz + a1[q] + bh_z)));
      const float n   = tanhf(in + rg_ * (a2[q] + bh_n));
      h[q] = (1.f - zg) * n + zg * h[q];
      const bf16_t hi = f2bf(h[q]);
      hbw[rr * 2048 + myj] = hi;
      hbw[rr * 2048 + 1024 + myj] = f2bf(h[q] - (float)hi);
    }
    grid.sync();
  }

#pragma unroll
  for (int q = 0; q < 4; ++q) {
    const int r = rbase + q;
    Hf[(size_t)r * 1024 + myj] = h[q];
    if (myj < 512) outp[(size_t)r * 512 + myj] = h[q];
    else           outp[262144 + (size_t)r * 512 + (myj - 512)] = h[q];
  }
}

// per-row LayerNorm(+bias) + LeakyReLU(0.1), row width 1024.
template<bool SPLIT>
__global__ __launch_bounds__(256)
void ln_leaky(const float* __restrict__ pre, const float* __restrict__ b,
              const float* __restrict__ g, const float* __restrict__ bet,
              bf16_t* __restrict__ outB, float* __restrict__ zf)
{
  const int row = blockIdx.x;
  const int tid = threadIdx.x;
  const float* p = pre + (size_t)row * 1024;
  float v[4];
  float s = 0.f, s2 = 0.f;
#pragma unroll
  for (int i = 0; i < 4; ++i) {
    const int c = tid + i * 256;
    v[i] = p[c] + b[c];
    s += v[i]; s2 += v[i] * v[i];
  }
#pragma unroll
  for (int o = 32; o; o >>= 1) { s += __shfl_down(s, o); s2 += __shfl_down(s2, o); }
  __shared__ float rs[4], rs2[4];
  if ((tid & 63) == 0) { rs[tid >> 6] = s; rs2[tid >> 6] = s2; }
  __syncthreads();
  s = rs[0] + rs[1] + rs[2] + rs[3];
  s2 = rs2[0] + rs2[1] + rs2[2] + rs2[3];
  const float mu = s * (1.f / 1024.f);
  const float var = s2 * (1.f / 1024.f) - mu * mu;
  const float rstd = rsqrtf(var + 1e-5f);
#pragma unroll
  for (int i = 0; i < 4; ++i) {
    const int c = tid + i * 256;
    float h = (v[i] - mu) * rstd * g[c] + bet[c];
    h = h >= 0.f ? h : 0.1f * h;
    if constexpr (SPLIT) {
      const bf16_t hi = f2bf(h);
      outB[(size_t)row * 2048 + c] = hi;
      outB[(size_t)row * 2048 + 1024 + c] = f2bf(h - (float)hi);
      zf[(size_t)row * 1024 + c] = h;
    } else {
      outB[(size_t)row * 1024 + c] = f2bf(h);
    }
  }
}

__global__ __launch_bounds__(256)
void transpose_bf16(const float* __restrict__ in, bf16_t* __restrict__ out, int R, int C)
{
  __shared__ float t[32][33];
  const int c0 = blockIdx.x * 32, r0 = blockIdx.y * 32;
  const int tx = threadIdx.x & 31, ty = threadIdx.x >> 5;
#pragma unroll
  for (int i = 0; i < 32; i += 8)
    t[ty + i][tx] = in[(size_t)(r0 + ty + i) * C + c0 + tx];
  __syncthreads();
#pragma unroll
  for (int i = 0; i < 32; i += 8)
    out[(size_t)(c0 + ty + i) * R + r0 + tx] = f2bf(t[tx][ty + i]);
}

__global__ __launch_bounds__(256)
void f2b_kernel(const float* __restrict__ in, bf16_t* __restrict__ out, int n)
{
  const int i = blockIdx.x * 256 + threadIdx.x;
  if (i < n) out[i] = f2bf(in[i]);
}

__global__ __launch_bounds__(256)
void dup2_kernel(const bf16_t* __restrict__ in, bf16_t* __restrict__ out, int N, int K)
{
  const int idx = blockIdx.x * 256 + threadIdx.x;
  if (idx >= N * 2 * K) return;
  const int n = idx / (2 * K);
  const int kk = idx - n * 2 * K;
  const int k = kk < K ? kk : kk - K;
  out[idx] = in[(size_t)n * K + k];
}

__global__ void sentinel_kernel(float* out, float code) {
  if (threadIdx.x == 0 && blockIdx.x == 0) out[0] = code;
}

extern "C" void kernel_launch(void* const* d_in, const int* in_sizes, int n_in,
                              void* d_out, int out_size, void* d_ws, size_t ws_size,
                              hipStream_t stream)
{
  const float* xs    = (const float*)d_in[0];
  const float* obs_W = (const float*)d_in[1];
  const float* obs_b = (const float*)d_in[2];
  const float* obs_g = (const float*)d_in[3];
  const float* obs_be= (const float*)d_in[4];
  const float* lat_W = (const float*)d_in[5];
  const float* lat_b = (const float*)d_in[6];
  const float* lat_g = (const float*)d_in[7];
  const float* lat_be= (const float*)d_in[8];
  const float* W0    = (const float*)d_in[9];
  const float* b0    = (const float*)d_in[10];
  const float* W1    = (const float*)d_in[11];
  const float* b1    = (const float*)d_in[12];
  const float* W2    = (const float*)d_in[13];
  const float* b2    = (const float*)d_in[14];
  const float* Wih   = (const float*)d_in[15];
  const float* Whh   = (const float*)d_in[16];
  const float* bih   = (const float*)d_in[17];
  const float* bhh   = (const float*)d_in[18];

  char* ws = (char*)d_ws;
  size_t off = 0;
  auto alloc = [&](size_t bytes) { char* p = ws + off; off += bytes; return p; };

  // ---- static region (~76 MB) ----
  bf16_t* OBSWT = (bf16_t*)alloc((size_t)HID * OBS * 2);
  bf16_t* LATWT = (bf16_t*)alloc((size_t)STATEDIM * HID * 2);
  bf16_t* W0T2  = (bf16_t*)alloc((size_t)HID * 2048 * 2);
  bf16_t* W1T   = (bf16_t*)alloc((size_t)HID * HID * 2);
  bf16_t* W2T   = (bf16_t*)alloc((size_t)STATEDIM * HID * 2);
  bf16_t* WIH2  = (bf16_t*)alloc((size_t)3072 * 2048 * 2);
  bf16_t* WHHB  = (bf16_t*)alloc((size_t)3072 * 1024 * 2);
  float*  Hf    = (float*)alloc((size_t)512 * 1024 * 4);
  bf16_t* HB2   = (bf16_t*)alloc((size_t)2 * 512 * 2048 * 2);
  bf16_t* W0T   = (bf16_t*)alloc((size_t)HID * HID * 2);       // temp
  bf16_t* WIHB  = (bf16_t*)alloc((size_t)3072 * 1024 * 2);     // temp
  bf16_t* XSB   = (bf16_t*)alloc((size_t)ROWS * OBS * 2);      // bf16 input
  const size_t staticEnd = off;

  // ---- chunking: per-row arena A1(4096)+A2(4096)+H1(2048)+H2(2048)+S2(4096)
  //      = 16384 B; GI f32 (12288 B/row) overlaps A1+A2+H1+H2.
  int nc = -1;
  const int ncs[8] = {1, 2, 4, 8, 16, 32, 64, 128};
  for (int i = 0; i < 8; ++i) {
    const size_t R = (size_t)ROWS / ncs[i];
    if (staticEnd + R * 16384 <= ws_size) { nc = ncs[i]; break; }
  }
  if (nc < 0) {
    sentinel_kernel<<<1, 1, 0, stream>>>((float*)d_out,
                                         -(1000000.0f + (float)(ws_size >> 20)));
    return;
  }
  const int R = ROWS / nc;
  char* arena = ws + staticEnd;
  float*  A1f  = (float*)(arena);                       // pre-LN / ZN
  float*  A2f  = (float*)(arena + (size_t)R * 4096);    // z fp32
  bf16_t* H1b  = (bf16_t*)(arena + (size_t)R * 8192);
  bf16_t* H2b  = (bf16_t*)(arena + (size_t)R * 10240);
  bf16_t* S2b  = (bf16_t*)(arena + (size_t)R * 12288);  // split z / stage input
  float*  GIf  = (float*)(arena);                       // gi f32 overlaps A1..H2

  auto gemm = [&](int epi, const bf16_t* A, const bf16_t* Wt, const float* bias,
                  int M, int N, int K, float* oF, bf16_t* oB) {
    dim3 g((M / 256) * (N / 256)), b(512);
    switch (epi) {
      case EPI_F32:  gemm8<EPI_F32><<<g, b, 0, stream>>>(A, Wt, bias, M, N, K, oF, oB, A2f, A1f, S2b); break;
      case EPI_GI:   gemm8<EPI_GI><<<g, b, 0, stream>>>(A, Wt, bias, M, N, K, oF, oB, A2f, A1f, S2b); break;
      case EPI_TANH: gemm8<EPI_TANH><<<g, b, 0, stream>>>(A, Wt, bias, M, N, K, oF, oB, A2f, A1f, S2b); break;
      case EPI_K1:   gemm8<EPI_K1><<<g, b, 0, stream>>>(A, Wt, bias, M, N, K, oF, oB, A2f, A1f, S2b); break;
      case EPI_K2:   gemm8<EPI_K2><<<g, b, 0, stream>>>(A, Wt, bias, M, N, K, oF, oB, A2f, A1f, S2b); break;
      case EPI_K3:   gemm8<EPI_K3><<<g, b, 0, stream>>>(A, Wt, bias, M, N, K, oF, oB, A2f, A1f, S2b); break;
      case EPI_K4:   gemm8<EPI_K4><<<g, b, 0, stream>>>(A, Wt, bias, M, N, K, oF, oB, A2f, A1f, S2b); break;
    }
  };

  // ---- weight prep ----
  transpose_bf16<<<dim3(HID / 32, OBS / 32), 256, 0, stream>>>(obs_W, OBSWT, OBS, HID);
  transpose_bf16<<<dim3(STATEDIM / 32, HID / 32), 256, 0, stream>>>(lat_W, LATWT, HID, STATEDIM);
  transpose_bf16<<<dim3(HID / 32, STATEDIM / 32), 256, 0, stream>>>(W0, W0T, STATEDIM, HID);
  dup2_kernel<<<(HID * 2048) / 256, 256, 0, stream>>>(W0T, W0T2, HID, 1024);
  transpose_bf16<<<dim3(HID / 32, HID / 32), 256, 0, stream>>>(W1, W1T, HID, HID);
  transpose_bf16<<<dim3(STATEDIM / 32, HID / 32), 256, 0, stream>>>(W2, W2T, HID, STATEDIM);
  f2b_kernel<<<(3072 * 1024) / 256, 256, 0, stream>>>(Wih, WIHB, 3072 * 1024);
  dup2_kernel<<<(3072 * 2048) / 256, 256, 0, stream>>>(WIHB, WIH2, 3072, 1024);
  f2b_kernel<<<(3072 * 1024) / 256, 256, 0, stream>>>(Whh, WHHB, 3072 * 1024);
  f2b_kernel<<<(ROWS * OBS) / 256, 256, 0, stream>>>(xs, XSB, ROWS * OBS);

  hipMemsetAsync(Hf, 0, (size_t)512 * 1024 * 4, stream);
  hipMemsetAsync(HB2, 0, (size_t)2 * 512 * 2048 * 2, stream);
  const int TS = R / BATCHN;

  for (int c = 0; c < nc; ++c) {
    // encoder MLPs
    gemm(EPI_F32, XSB + (size_t)c * R * OBS, OBSWT, nullptr, R, HID, OBS, A1f, nullptr);
    ln_leaky<false><<<R, 256, 0, stream>>>(A1f, obs_b, obs_g, obs_be, H1b, nullptr);
    gemm(EPI_F32, H1b, LATWT, nullptr, R, STATEDIM, HID, A1f, nullptr);
    ln_leaky<true><<<R, 256, 0, stream>>>(A1f, lat_b, lat_g, lat_be, S2b, A2f);

    // RK4: 4 steps x 4 stages x 3 GEMMs
    for (int step = 0; step < 4; ++step) {
      for (int stg = 0; stg < 4; ++stg) {
        gemm(EPI_TANH, S2b, W0T2, b0, R, HID, 2048, nullptr, H1b);
        gemm(EPI_TANH, H1b, W1T, b1, R, HID, HID, nullptr, H2b);
        gemm(EPI_K1 + stg, H2b, W2T, b2, R, STATEDIM, HID, nullptr, nullptr);
      }
    }

    // gi = z_final @ Wih^T + bih (split-z, f32 out) — overwrites dead A1..H2
    gemm(EPI_GI, S2b, WIH2, bih, R, 3072, 2048, GIf, nullptr);

    // persistent GRU over this chunk's timesteps
    {
      const float* giArg = GIf;
      const bf16_t* whhArg = WHHB;
      const float* bhhArg = bhh;
      float* hfArg = Hf;
      bf16_t* hbArg = HB2;
      float* outArg = (float*)d_out;
      int tsArg = TS;
      int t0Arg = c * TS;
      void* args[] = { (void*)&giArg, (void*)&whhArg, (void*)&bhhArg,
                       (void*)&hfArg, (void*)&hbArg, (void*)&outArg,
                       (void*)&tsArg, (void*)&t0Arg };
      hipLaunchCooperativeKernel((const void*)gru_persistent,
                                 dim3(256), dim3(512), args, 0, stream);
    }
  }
}

// Round 6
// 25606.479 us; speedup vs baseline: 1.3611x; 1.2552x over previous
//
#include <hip/hip_runtime.h>
#include <hip/hip_bf16.h>
#include <hip/hip_cooperative_groups.h>

namespace cg = cooperative_groups;

typedef __bf16 bf16_t;
typedef __bf16 bf16x8 __attribute__((ext_vector_type(8)));
typedef float f32x4 __attribute__((ext_vector_type(4)));

#define TLEN 128
#define BATCHN 512
#define OBS 256
#define HID 1024
#define STATEDIM 1024
#define ROWS (TLEN * BATCHN)   // 65536
#define RKDT 0.25f

enum { EPI_F32 = 0, EPI_GI, EPI_TANH, EPI_K1, EPI_K2, EPI_K3, EPI_K4 };

__device__ __forceinline__ void gload_lds16(const bf16_t* g, bf16_t* l) {
  __builtin_amdgcn_global_load_lds(
      (const __attribute__((address_space(1))) void*)g,
      (__attribute__((address_space(3))) void*)l, 16, 0, 0);
}

__device__ __forceinline__ bf16_t f2bf(float x) { return (bf16_t)x; }

// fast tanh/sigmoid on v_exp_f32 (~1e-6 abs err; bf16-invisible)
__device__ __forceinline__ float fast_tanh(float x) {
  const float e = __expf(2.f * x);
  return 1.f - 2.f / (e + 1.f);
}
__device__ __forceinline__ float fast_sigmoid(float x) {
  return 1.f / (1.f + __expf(-x));
}

#define MF(a_, b_, c_) __builtin_amdgcn_mfma_f32_16x16x32_bf16(a_, b_, c_, 0, 0, 0)

// ============================================================================
// m97-structure GEMM (proven r2 kernel) + bijective XCD chunk-swizzle (T1).
// C = epi(A[M][K] @ Wt[N][K]^T + bias). A,Wt bf16 row-major, fp32 acc.
// 128x128 tile, BK=32, 4 waves (2x2), 16x16x32 MFMA, global_load_lds dbuf.
// Swizzle rationale: bid=bm*nbn+bn -> nbn consecutive blocks share the A-panel;
// chunked per-XCD mapping makes those neighbors co-XCD -> A-panel L2 hits.
// ============================================================================
template<int EPI>
__global__ __launch_bounds__(256)
void gemm_bt(const bf16_t* __restrict__ A, const bf16_t* __restrict__ Wt,
             const float* __restrict__ bias, int M, int N, int K,
             float* __restrict__ outF, bf16_t* __restrict__ outB,
             float* __restrict__ Z, float* __restrict__ ZN,
             bf16_t* __restrict__ S2)
{
  __shared__ __align__(16) bf16_t As[2][128 * 32];
  __shared__ __align__(16) bf16_t Bs[2][128 * 32];
  const int tid = threadIdx.x;
  const int lane = tid & 63;
  const int wave = tid >> 6;
  const int nbn = N >> 7;

  // bijective XCD swizzle (m204): contiguous chunk of blocks per XCD
  int bid = blockIdx.x;
  {
    const int nwg = gridDim.x;
    const int q = nwg >> 3, r = nwg & 7;
    const int xcd = bid & 7, lid = bid >> 3;
    bid = (xcd < r ? xcd * (q + 1) : r * (q + 1) + (xcd - r) * q) + lid;
  }
  const int bm = bid / nbn;
  const int bn = bid % nbn;
  const int m0 = bm << 7, n0 = bn << 7;
  const int wr = wave >> 1, wc = wave & 1;
  const int srow = tid >> 2;          // staging row in tile (0..63)
  const int scol = (tid & 3) << 3;    // staging col (bf16 elems)

  f32x4 acc[4][4] = {};
  const int nk = K >> 5;
  int cur = 0;

  {
    const bf16_t* ga = A  + (size_t)(m0 + srow) * K + scol;
    const bf16_t* gb = Wt + (size_t)(n0 + srow) * K + scol;
    bf16_t* la = &As[0][tid * 8];
    bf16_t* lb = &Bs[0][tid * 8];
    gload_lds16(ga, la);
    gload_lds16(ga + (size_t)64 * K, la + 2048);
    gload_lds16(gb, lb);
    gload_lds16(gb + (size_t)64 * K, lb + 2048);
  }

  for (int ks = 0; ks < nk; ++ks) {
    __syncthreads();  // drains vmcnt(0): staged tile ready
    if (ks + 1 < nk) {
      const bf16_t* ga = A  + (size_t)(m0 + srow) * K + (ks + 1) * 32 + scol;
      const bf16_t* gb = Wt + (size_t)(n0 + srow) * K + (ks + 1) * 32 + scol;
      bf16_t* la = &As[cur ^ 1][tid * 8];
      bf16_t* lb = &Bs[cur ^ 1][tid * 8];
      gload_lds16(ga, la);
      gload_lds16(ga + (size_t)64 * K, la + 2048);
      gload_lds16(gb, lb);
      gload_lds16(gb + (size_t)64 * K, lb + 2048);
    }
    const int kb = (lane >> 4) << 3;
    const int rr = lane & 15;
    bf16x8 af[4], bfr[4];
#pragma unroll
    for (int i = 0; i < 4; ++i) {
      af[i]  = *(const bf16x8*)&As[cur][(wr * 64 + i * 16 + rr) * 32 + kb];
      bfr[i] = *(const bf16x8*)&Bs[cur][(wc * 64 + i * 16 + rr) * 32 + kb];
    }
#pragma unroll
    for (int i = 0; i < 4; ++i)
#pragma unroll
      for (int j = 0; j < 4; ++j)
        acc[i][j] = MF(af[i], bfr[j], acc[i][j]);
    cur ^= 1;
  }

  // C/D layout: col=lane&15, row=(lane>>4)*4+reg  [m89-verified]
  const int cb = n0 + wc * 64 + (lane & 15);
  const int rb = m0 + wr * 64 + ((lane >> 4) << 2);
#pragma unroll
  for (int j = 0; j < 4; ++j) {
    const int c = cb + j * 16;
    float bv = 0.f;
    if constexpr (EPI != EPI_F32) bv = bias[c];
#pragma unroll
    for (int i = 0; i < 4; ++i) {
      const int r0 = rb + i * 16;
#pragma unroll
      for (int r = 0; r < 4; ++r) {
        const size_t idx = (size_t)(r0 + r) * N + c;
        const float v = acc[i][j][r];
        if constexpr (EPI == EPI_F32) {
          outF[idx] = v;
        } else if constexpr (EPI == EPI_GI) {
          outF[idx] = v + bv;
        } else if constexpr (EPI == EPI_TANH) {
          outB[idx] = f2bf(fast_tanh(v + bv));
        } else {
          const float k = v + bv;          // N==1024 here; idx = row*1024+c
          const size_t si = (size_t)(r0 + r) * 2048 + c;
          float s;
          if constexpr (EPI == EPI_K1) {
            const float z = Z[idx];
            ZN[idx] = z + (RKDT / 6.f) * k;
            s = z + 0.5f * RKDT * k;
          } else if constexpr (EPI == EPI_K2) {
            const float z = Z[idx];
            ZN[idx] += (RKDT / 3.f) * k;
            s = z + 0.5f * RKDT * k;
          } else if constexpr (EPI == EPI_K3) {
            const float z = Z[idx];
            ZN[idx] += (RKDT / 3.f) * k;
            s = z + RKDT * k;
          } else {  // K4
            s = ZN[idx] + (RKDT / 6.f) * k;
            Z[idx] = s;
          }
          const bf16_t hi = f2bf(s);
          S2[si] = hi;
          S2[si + 1024] = f2bf(s - (float)hi);
        }
      }
    }
  }
}

// Persistent GRU: whole recurrence in one cooperative launch (proven r3).
__global__ __launch_bounds__(512)
void gru_persistent(const float* __restrict__ gi,   // [TS][512][3072] (bih incl)
                    const bf16_t* __restrict__ Whh, // [3072][1024] bf16
                    const float* __restrict__ bhh,  // [3072]
                    float* __restrict__ Hf,         // [512][1024] f32 persist
                    bf16_t* __restrict__ hb,        // [2][512][2048] split h
                    float* __restrict__ outp,       // d_out (f32)
                    int TS, int t0)
{
  __shared__ __align__(16) bf16_t Bs[48 * 1032];
  const int tid  = threadIdx.x;
  const int lane = tid & 63;
  const int w    = tid >> 6;
  const int rg   = blockIdx.x >> 6;
  const int jg   = blockIdx.x & 63;
  const int r0   = rg << 7;
  const int j0   = jg << 4;

  for (int it = tid; it < 48 * 128; it += 512) {
    const int rr = it >> 7;
    const int co = (it & 127) << 3;
    const int g = rr >> 4, c = rr & 15;
    *(bf16x8*)&Bs[rr * 1032 + co] =
        *(const bf16x8*)&Whh[(size_t)(g * 1024 + j0 + c) * 1024 + co];
  }

  const int myj = j0 + (lane & 15);
  const float bh_r = bhh[myj], bh_z = bhh[1024 + myj], bh_n = bhh[2048 + myj];
  const int rbase = r0 + w * 16 + ((lane >> 4) << 2);

  float h[4];
#pragma unroll
  for (int q = 0; q < 4; ++q) h[q] = Hf[(size_t)(rbase + q) * 1024 + myj];

  __syncthreads();
  cg::grid_group grid = cg::this_grid();

  const int arow = r0 + w * 16 + (lane & 15);
  const int akoff = (lane >> 4) << 3;

  for (int t = t0; t < t0 + TS; ++t) {
    const bf16_t* ap = hb + (size_t)(t & 1) * 512 * 2048 +
                       (size_t)arow * 2048 + akoff;
    f32x4 a0 = {}, a1 = {}, a2 = {};
    const bf16_t* bp0 = &Bs[(0  + (lane & 15)) * 1032 + akoff];
    const bf16_t* bp1 = &Bs[(16 + (lane & 15)) * 1032 + akoff];
    const bf16_t* bp2 = &Bs[(32 + (lane & 15)) * 1032 + akoff];
#pragma unroll 8
    for (int kc = 0; kc < 64; ++kc) {
      const bf16x8 af = *(const bf16x8*)(ap + kc * 32);
      const int kl = (kc * 32) & 1023;
      a0 = MF(af, *(const bf16x8*)(bp0 + kl), a0);
      a1 = MF(af, *(const bf16x8*)(bp1 + kl), a1);
      a2 = MF(af, *(const bf16x8*)(bp2 + kl), a2);
    }
    const float* gir = gi + (size_t)(t - t0) * 512 * 3072;
    bf16_t* hbw = hb + (size_t)((t + 1) & 1) * 512 * 2048;
#pragma unroll
    for (int q = 0; q < 4; ++q) {
      const size_t rr = (size_t)(rbase + q);
      const float ir = gir[rr * 3072 + myj];
      const float iz = gir[rr * 3072 + 1024 + myj];
      const float in = gir[rr * 3072 + 2048 + myj];
      const float rg_ = fast_sigmoid(ir + a0[q] + bh_r);
      const float zg  = fast_sigmoid(iz + a1[q] + bh_z);
      const float n   = fast_tanh(in + rg_ * (a2[q] + bh_n));
      h[q] = (1.f - zg) * n + zg * h[q];
      const bf16_t hi = f2bf(h[q]);
      hbw[rr * 2048 + myj] = hi;
      hbw[rr * 2048 + 1024 + myj] = f2bf(h[q] - (float)hi);
    }
    grid.sync();
  }

#pragma unroll
  for (int q = 0; q < 4; ++q) {
    const int r = rbase + q;
    Hf[(size_t)r * 1024 + myj] = h[q];
    if (myj < 512) outp[(size_t)r * 512 + myj] = h[q];
    else           outp[262144 + (size_t)r * 512 + (myj - 512)] = h[q];
  }
}

// per-row LayerNorm(+bias) + LeakyReLU(0.1), row width 1024.
template<bool SPLIT>
__global__ __launch_bounds__(256)
void ln_leaky(const float* __restrict__ pre, const float* __restrict__ b,
              const float* __restrict__ g, const float* __restrict__ bet,
              bf16_t* __restrict__ outB, float* __restrict__ zf)
{
  const int row = blockIdx.x;
  const int tid = threadIdx.x;
  const float* p = pre + (size_t)row * 1024;
  float v[4];
  float s = 0.f, s2 = 0.f;
#pragma unroll
  for (int i = 0; i < 4; ++i) {
    const int c = tid + i * 256;
    v[i] = p[c] + b[c];
    s += v[i]; s2 += v[i] * v[i];
  }
#pragma unroll
  for (int o = 32; o; o >>= 1) { s += __shfl_down(s, o); s2 += __shfl_down(s2, o); }
  __shared__ float rs[4], rs2[4];
  if ((tid & 63) == 0) { rs[tid >> 6] = s; rs2[tid >> 6] = s2; }
  __syncthreads();
  s = rs[0] + rs[1] + rs[2] + rs[3];
  s2 = rs2[0] + rs2[1] + rs2[2] + rs2[3];
  const float mu = s * (1.f / 1024.f);
  const float var = s2 * (1.f / 1024.f) - mu * mu;
  const float rstd = rsqrtf(var + 1e-5f);
#pragma unroll
  for (int i = 0; i < 4; ++i) {
    const int c = tid + i * 256;
    float h = (v[i] - mu) * rstd * g[c] + bet[c];
    h = h >= 0.f ? h : 0.1f * h;
    if constexpr (SPLIT) {
      const bf16_t hi = f2bf(h);
      outB[(size_t)row * 2048 + c] = hi;
      outB[(size_t)row * 2048 + 1024 + c] = f2bf(h - (float)hi);
      zf[(size_t)row * 1024 + c] = h;
    } else {
      outB[(size_t)row * 1024 + c] = f2bf(h);
    }
  }
}

__global__ __launch_bounds__(256)
void transpose_bf16(const float* __restrict__ in, bf16_t* __restrict__ out, int R, int C)
{
  __shared__ float t[32][33];
  const int c0 = blockIdx.x * 32, r0 = blockIdx.y * 32;
  const int tx = threadIdx.x & 31, ty = threadIdx.x >> 5;
#pragma unroll
  for (int i = 0; i < 32; i += 8)
    t[ty + i][tx] = in[(size_t)(r0 + ty + i) * C + c0 + tx];
  __syncthreads();
#pragma unroll
  for (int i = 0; i < 32; i += 8)
    out[(size_t)(c0 + ty + i) * R + r0 + tx] = f2bf(t[tx][ty + i]);
}

__global__ __launch_bounds__(256)
void f2b_kernel(const float* __restrict__ in, bf16_t* __restrict__ out, int n)
{
  const int i = blockIdx.x * 256 + threadIdx.x;
  if (i < n) out[i] = f2bf(in[i]);
}

__global__ __launch_bounds__(256)
void dup2_kernel(const bf16_t* __restrict__ in, bf16_t* __restrict__ out, int N, int K)
{
  const int idx = blockIdx.x * 256 + threadIdx.x;
  if (idx >= N * 2 * K) return;
  const int n = idx / (2 * K);
  const int kk = idx - n * 2 * K;
  const int k = kk < K ? kk : kk - K;
  out[idx] = in[(size_t)n * K + k];
}

__global__ void sentinel_kernel(float* out, float code) {
  if (threadIdx.x == 0 && blockIdx.x == 0) out[0] = code;
}

extern "C" void kernel_launch(void* const* d_in, const int* in_sizes, int n_in,
                              void* d_out, int out_size, void* d_ws, size_t ws_size,
                              hipStream_t stream)
{
  const float* xs    = (const float*)d_in[0];
  const float* obs_W = (const float*)d_in[1];
  const float* obs_b = (const float*)d_in[2];
  const float* obs_g = (const float*)d_in[3];
  const float* obs_be= (const float*)d_in[4];
  const float* lat_W = (const float*)d_in[5];
  const float* lat_b = (const float*)d_in[6];
  const float* lat_g = (const float*)d_in[7];
  const float* lat_be= (const float*)d_in[8];
  const float* W0    = (const float*)d_in[9];
  const float* b0    = (const float*)d_in[10];
  const float* W1    = (const float*)d_in[11];
  const float* b1    = (const float*)d_in[12];
  const float* W2    = (const float*)d_in[13];
  const float* b2    = (const float*)d_in[14];
  const float* Wih   = (const float*)d_in[15];
  const float* Whh   = (const float*)d_in[16];
  const float* bih   = (const float*)d_in[17];
  const float* bhh   = (const float*)d_in[18];

  char* ws = (char*)d_ws;
  size_t off = 0;
  auto alloc = [&](size_t bytes) { char* p = ws + off; off += bytes; return p; };

  // ---- static region (~76 MB) ----
  bf16_t* OBSWT = (bf16_t*)alloc((size_t)HID * OBS * 2);
  bf16_t* LATWT = (bf16_t*)alloc((size_t)STATEDIM * HID * 2);
  bf16_t* W0T2  = (bf16_t*)alloc((size_t)HID * 2048 * 2);
  bf16_t* W1T   = (bf16_t*)alloc((size_t)HID * HID * 2);
  bf16_t* W2T   = (bf16_t*)alloc((size_t)STATEDIM * HID * 2);
  bf16_t* WIH2  = (bf16_t*)alloc((size_t)3072 * 2048 * 2);
  bf16_t* WHHB  = (bf16_t*)alloc((size_t)3072 * 1024 * 2);
  float*  Hf    = (float*)alloc((size_t)512 * 1024 * 4);
  bf16_t* HB2   = (bf16_t*)alloc((size_t)2 * 512 * 2048 * 2);
  bf16_t* W0T   = (bf16_t*)alloc((size_t)HID * HID * 2);       // temp
  bf16_t* WIHB  = (bf16_t*)alloc((size_t)3072 * 1024 * 2);     // temp
  bf16_t* XSB   = (bf16_t*)alloc((size_t)ROWS * OBS * 2);      // bf16 input
  const size_t staticEnd = off;

  // ---- chunking: per-row arena A1(4096)+A2(4096)+H1(2048)+H2(2048)+S2(4096)
  //      = 16384 B; GI f32 (12288 B/row) overlaps A1+A2+H1+H2.
  int nc = -1;
  const int ncs[8] = {1, 2, 4, 8, 16, 32, 64, 128};
  for (int i = 0; i < 8; ++i) {
    const size_t R = (size_t)ROWS / ncs[i];
    if (staticEnd + R * 16384 <= ws_size) { nc = ncs[i]; break; }
  }
  if (nc < 0) {
    sentinel_kernel<<<1, 1, 0, stream>>>((float*)d_out,
                                         -(1000000.0f + (float)(ws_size >> 20)));
    return;
  }
  const int R = ROWS / nc;
  char* arena = ws + staticEnd;
  float*  A1f  = (float*)(arena);                       // pre-LN / ZN
  float*  A2f  = (float*)(arena + (size_t)R * 4096);    // z fp32
  bf16_t* H1b  = (bf16_t*)(arena + (size_t)R * 8192);
  bf16_t* H2b  = (bf16_t*)(arena + (size_t)R * 10240);
  bf16_t* S2b  = (bf16_t*)(arena + (size_t)R * 12288);  // split z / stage input
  float*  GIf  = (float*)(arena);                       // gi f32 overlaps A1..H2

  auto gemm = [&](int epi, const bf16_t* A, const bf16_t* Wt, const float* bias,
                  int M, int N, int K, float* oF, bf16_t* oB) {
    dim3 g((M / 128) * (N / 128)), b(256);
    switch (epi) {
      case EPI_F32:  gemm_bt<EPI_F32><<<g, b, 0, stream>>>(A, Wt, bias, M, N, K, oF, oB, A2f, A1f, S2b); break;
      case EPI_GI:   gemm_bt<EPI_GI><<<g, b, 0, stream>>>(A, Wt, bias, M, N, K, oF, oB, A2f, A1f, S2b); break;
      case EPI_TANH: gemm_bt<EPI_TANH><<<g, b, 0, stream>>>(A, Wt, bias, M, N, K, oF, oB, A2f, A1f, S2b); break;
      case EPI_K1:   gemm_bt<EPI_K1><<<g, b, 0, stream>>>(A, Wt, bias, M, N, K, oF, oB, A2f, A1f, S2b); break;
      case EPI_K2:   gemm_bt<EPI_K2><<<g, b, 0, stream>>>(A, Wt, bias, M, N, K, oF, oB, A2f, A1f, S2b); break;
      case EPI_K3:   gemm_bt<EPI_K3><<<g, b, 0, stream>>>(A, Wt, bias, M, N, K, oF, oB, A2f, A1f, S2b); break;
      case EPI_K4:   gemm_bt<EPI_K4><<<g, b, 0, stream>>>(A, Wt, bias, M, N, K, oF, oB, A2f, A1f, S2b); break;
    }
  };

  // ---- weight prep ----
  transpose_bf16<<<dim3(HID / 32, OBS / 32), 256, 0, stream>>>(obs_W, OBSWT, OBS, HID);
  transpose_bf16<<<dim3(STATEDIM / 32, HID / 32), 256, 0, stream>>>(lat_W, LATWT, HID, STATEDIM);
  transpose_bf16<<<dim3(HID / 32, STATEDIM / 32), 256, 0, stream>>>(W0, W0T, STATEDIM, HID);
  dup2_kernel<<<(HID * 2048) / 256, 256, 0, stream>>>(W0T, W0T2, HID, 1024);
  transpose_bf16<<<dim3(HID / 32, HID / 32), 256, 0, stream>>>(W1, W1T, HID, HID);
  transpose_bf16<<<dim3(STATEDIM / 32, HID / 32), 256, 0, stream>>>(W2, W2T, HID, STATEDIM);
  f2b_kernel<<<(3072 * 1024) / 256, 256, 0, stream>>>(Wih, WIHB, 3072 * 1024);
  dup2_kernel<<<(3072 * 2048) / 256, 256, 0, stream>>>(WIHB, WIH2, 3072, 1024);
  f2b_kernel<<<(3072 * 1024) / 256, 256, 0, stream>>>(Whh, WHHB, 3072 * 1024);
  f2b_kernel<<<(ROWS * OBS) / 256, 256, 0, stream>>>(xs, XSB, ROWS * OBS);

  hipMemsetAsync(Hf, 0, (size_t)512 * 1024 * 4, stream);
  hipMemsetAsync(HB2, 0, (size_t)2 * 512 * 2048 * 2, stream);
  const int TS = R / BATCHN;

  for (int c = 0; c < nc; ++c) {
    // encoder MLPs
    gemm(EPI_F32, XSB + (size_t)c * R * OBS, OBSWT, nullptr, R, HID, OBS, A1f, nullptr);
    ln_leaky<false><<<R, 256, 0, stream>>>(A1f, obs_b, obs_g, obs_be, H1b, nullptr);
    gemm(EPI_F32, H1b, LATWT, nullptr, R, STATEDIM, HID, A1f, nullptr);
    ln_leaky<true><<<R, 256, 0, stream>>>(A1f, lat_b, lat_g, lat_be, S2b, A2f);

    // RK4: 4 steps x 4 stages x 3 GEMMs
    for (int step = 0; step < 4; ++step) {
      for (int stg = 0; stg < 4; ++stg) {
        gemm(EPI_TANH, S2b, W0T2, b0, R, HID, 2048, nullptr, H1b);
        gemm(EPI_TANH, H1b, W1T, b1, R, HID, HID, nullptr, H2b);
        gemm(EPI_K1 + stg, H2b, W2T, b2, R, STATEDIM, HID, nullptr, nullptr);
      }
    }

    // gi = z_final @ Wih^T + bih (split-z, f32 out) — overwrites dead A1..H2
    gemm(EPI_GI, S2b, WIH2, bih, R, 3072, 2048, GIf, nullptr);

    // persistent GRU over this chunk's timesteps
    {
      const float* giArg = GIf;
      const bf16_t* whhArg = WHHB;
      const float* bhhArg = bhh;
      float* hfArg = Hf;
      bf16_t* hbArg = HB2;
      float* outArg = (float*)d_out;
      int tsArg = TS;
      int t0Arg = c * TS;
      void* args[] = { (void*)&giArg, (void*)&whhArg, (void*)&bhhArg,
                       (void*)&hfArg, (void*)&hbArg, (void*)&outArg,
                       (void*)&tsArg, (void*)&t0Arg };
      hipLaunchCooperativeKernel((const void*)gru_persistent,
                                 dim3(256), dim3(512), args, 0, stream);
    }
  }
}

// Round 7
// 21628.735 us; speedup vs baseline: 1.6115x; 1.1839x over previous
//
#include <hip/hip_runtime.h>
#include <hip/hip_bf16.h>
#include <hip/hip_cooperative_groups.h>

namespace cg = cooperative_groups;

typedef __bf16 bf16_t;
typedef __bf16 bf16x8 __attribute__((ext_vector_type(8)));
typedef float f32x4 __attribute__((ext_vector_type(4)));

#define TLEN 128
#define BATCHN 512
#define OBS 256
#define HID 1024
#define STATEDIM 1024
#define ROWS (TLEN * BATCHN)   // 65536
#define RKDT 0.25f

// EPI_Z0: Z0f=v+b (f32) AND h1=tanh(v+b) (fused stage-1)
// EPI_KG: h1 = tanh(Z0f + kgc*v)   (G = k@W0, no bias)
// EPI_K1..K3: zn update + write k as plain bf16
// EPI_K4: final z; write split-bf16 S2
enum { EPI_F32 = 0, EPI_GI, EPI_TANH, EPI_Z0, EPI_KG, EPI_K1, EPI_K2, EPI_K3, EPI_K4 };

__device__ __forceinline__ void gload_lds16(const bf16_t* g, bf16_t* l) {
  __builtin_amdgcn_global_load_lds(
      (const __attribute__((address_space(1))) void*)g,
      (__attribute__((address_space(3))) void*)l, 16, 0, 0);
}

__device__ __forceinline__ bf16_t f2bf(float x) { return (bf16_t)x; }

// fast tanh/sigmoid on v_exp_f32 (~1e-6 abs err; bf16-invisible)
__device__ __forceinline__ float fast_tanh(float x) {
  const float e = __expf(2.f * x);
  return 1.f - 2.f / (e + 1.f);
}
__device__ __forceinline__ float fast_sigmoid(float x) {
  return 1.f / (1.f + __expf(-x));
}

#define MF(a_, b_, c_) __builtin_amdgcn_mfma_f32_16x16x32_bf16(a_, b_, c_, 0, 0, 0)

// ============================================================================
// m97-structure GEMM + bijective XCD chunk-swizzle (proven r6 kernel).
// C = epi(A[M][K] @ Wt[N][K]^T + bias). A,Wt bf16 row-major, fp32 acc.
// 128x128 tile, BK=32, 4 waves (2x2), 16x16x32 MFMA, global_load_lds dbuf.
// ============================================================================
template<int EPI>
__global__ __launch_bounds__(256)
void gemm_bt(const bf16_t* __restrict__ A, const bf16_t* __restrict__ Wt,
             const float* __restrict__ bias, int M, int N, int K,
             float* __restrict__ outF, bf16_t* __restrict__ outB,
             float* __restrict__ Z, float* __restrict__ ZN,
             bf16_t* __restrict__ S2, const float* __restrict__ Z0,
             float kgc)
{
  __shared__ __align__(16) bf16_t As[2][128 * 32];
  __shared__ __align__(16) bf16_t Bs[2][128 * 32];
  const int tid = threadIdx.x;
  const int lane = tid & 63;
  const int wave = tid >> 6;
  const int nbn = N >> 7;

  // bijective XCD swizzle (m204): contiguous chunk of blocks per XCD
  int bid = blockIdx.x;
  {
    const int nwg = gridDim.x;
    const int q = nwg >> 3, r = nwg & 7;
    const int xcd = bid & 7, lid = bid >> 3;
    bid = (xcd < r ? xcd * (q + 1) : r * (q + 1) + (xcd - r) * q) + lid;
  }
  const int bm = bid / nbn;
  const int bn = bid % nbn;
  const int m0 = bm << 7, n0 = bn << 7;
  const int wr = wave >> 1, wc = wave & 1;
  const int srow = tid >> 2;          // staging row in tile (0..63)
  const int scol = (tid & 3) << 3;    // staging col (bf16 elems)

  f32x4 acc[4][4] = {};
  const int nk = K >> 5;
  int cur = 0;

  {
    const bf16_t* ga = A  + (size_t)(m0 + srow) * K + scol;
    const bf16_t* gb = Wt + (size_t)(n0 + srow) * K + scol;
    bf16_t* la = &As[0][tid * 8];
    bf16_t* lb = &Bs[0][tid * 8];
    gload_lds16(ga, la);
    gload_lds16(ga + (size_t)64 * K, la + 2048);
    gload_lds16(gb, lb);
    gload_lds16(gb + (size_t)64 * K, lb + 2048);
  }

  for (int ks = 0; ks < nk; ++ks) {
    __syncthreads();  // drains vmcnt(0): staged tile ready
    if (ks + 1 < nk) {
      const bf16_t* ga = A  + (size_t)(m0 + srow) * K + (ks + 1) * 32 + scol;
      const bf16_t* gb = Wt + (size_t)(n0 + srow) * K + (ks + 1) * 32 + scol;
      bf16_t* la = &As[cur ^ 1][tid * 8];
      bf16_t* lb = &Bs[cur ^ 1][tid * 8];
      gload_lds16(ga, la);
      gload_lds16(ga + (size_t)64 * K, la + 2048);
      gload_lds16(gb, lb);
      gload_lds16(gb + (size_t)64 * K, lb + 2048);
    }
    const int kb = (lane >> 4) << 3;
    const int rr = lane & 15;
    bf16x8 af[4], bfr[4];
#pragma unroll
    for (int i = 0; i < 4; ++i) {
      af[i]  = *(const bf16x8*)&As[cur][(wr * 64 + i * 16 + rr) * 32 + kb];
      bfr[i] = *(const bf16x8*)&Bs[cur][(wc * 64 + i * 16 + rr) * 32 + kb];
    }
#pragma unroll
    for (int i = 0; i < 4; ++i)
#pragma unroll
      for (int j = 0; j < 4; ++j)
        acc[i][j] = MF(af[i], bfr[j], acc[i][j]);
    cur ^= 1;
  }

  // C/D layout: col=lane&15, row=(lane>>4)*4+reg  [m89-verified]
  const int cb = n0 + wc * 64 + (lane & 15);
  const int rb = m0 + wr * 64 + ((lane >> 4) << 2);
#pragma unroll
  for (int j = 0; j < 4; ++j) {
    const int c = cb + j * 16;
    float bv = 0.f;
    if constexpr (EPI != EPI_F32 && EPI != EPI_KG) bv = bias[c];
#pragma unroll
    for (int i = 0; i < 4; ++i) {
      const int r0 = rb + i * 16;
#pragma unroll
      for (int r = 0; r < 4; ++r) {
        const size_t idx = (size_t)(r0 + r) * N + c;
        const float v = acc[i][j][r];
        if constexpr (EPI == EPI_F32) {
          outF[idx] = v;
        } else if constexpr (EPI == EPI_GI) {
          outF[idx] = v + bv;
        } else if constexpr (EPI == EPI_TANH) {
          outB[idx] = f2bf(fast_tanh(v + bv));
        } else if constexpr (EPI == EPI_Z0) {
          const float t = v + bv;
          outF[idx] = t;                         // Z0f (f32, reused 3x)
          outB[idx] = f2bf(fast_tanh(t));        // fused stage-1 h1
        } else if constexpr (EPI == EPI_KG) {
          outB[idx] = f2bf(fast_tanh(Z0[idx] + kgc * v));
        } else if constexpr (EPI == EPI_K1) {
          const float k = v + bv;
          ZN[idx] = Z[idx] + (RKDT / 6.f) * k;
          outB[idx] = f2bf(k);                   // k1 plain bf16
        } else if constexpr (EPI == EPI_K2 || EPI == EPI_K3) {
          const float k = v + bv;
          ZN[idx] += (RKDT / 3.f) * k;
          outB[idx] = f2bf(k);
        } else {  // EPI_K4: final z of this RK4 step
          const float k = v + bv;
          const float s = ZN[idx] + (RKDT / 6.f) * k;
          Z[idx] = s;
          const size_t si = (size_t)(r0 + r) * 2048 + c;
          const bf16_t hi = f2bf(s);
          S2[si] = hi;
          S2[si + 1024] = f2bf(s - (float)hi);
        }
      }
    }
  }
}

// Persistent GRU: whole recurrence in one cooperative launch (proven r3/r6).
__global__ __launch_bounds__(512)
void gru_persistent(const float* __restrict__ gi,   // [TS][512][3072] (bih incl)
                    const bf16_t* __restrict__ Whh, // [3072][1024] bf16
                    const float* __restrict__ bhh,  // [3072]
                    float* __restrict__ Hf,         // [512][1024] f32 persist
                    bf16_t* __restrict__ hb,        // [2][512][2048] split h
                    float* __restrict__ outp,       // d_out (f32)
                    int TS, int t0)
{
  __shared__ __align__(16) bf16_t Bs[48 * 1032];
  const int tid  = threadIdx.x;
  const int lane = tid & 63;
  const int w    = tid >> 6;
  const int rg   = blockIdx.x >> 6;
  const int jg   = blockIdx.x & 63;
  const int r0   = rg << 7;
  const int j0   = jg << 4;

  for (int it = tid; it < 48 * 128; it += 512) {
    const int rr = it >> 7;
    const int co = (it & 127) << 3;
    const int g = rr >> 4, c = rr & 15;
    *(bf16x8*)&Bs[rr * 1032 + co] =
        *(const bf16x8*)&Whh[(size_t)(g * 1024 + j0 + c) * 1024 + co];
  }

  const int myj = j0 + (lane & 15);
  const float bh_r = bhh[myj], bh_z = bhh[1024 + myj], bh_n = bhh[2048 + myj];
  const int rbase = r0 + w * 16 + ((lane >> 4) << 2);

  float h[4];
#pragma unroll
  for (int q = 0; q < 4; ++q) h[q] = Hf[(size_t)(rbase + q) * 1024 + myj];

  __syncthreads();
  cg::grid_group grid = cg::this_grid();

  const int arow = r0 + w * 16 + (lane & 15);
  const int akoff = (lane >> 4) << 3;

  for (int t = t0; t < t0 + TS; ++t) {
    const bf16_t* ap = hb + (size_t)(t & 1) * 512 * 2048 +
                       (size_t)arow * 2048 + akoff;
    f32x4 a0 = {}, a1 = {}, a2 = {};
    const bf16_t* bp0 = &Bs[(0  + (lane & 15)) * 1032 + akoff];
    const bf16_t* bp1 = &Bs[(16 + (lane & 15)) * 1032 + akoff];
    const bf16_t* bp2 = &Bs[(32 + (lane & 15)) * 1032 + akoff];
#pragma unroll 8
    for (int kc = 0; kc < 64; ++kc) {
      const bf16x8 af = *(const bf16x8*)(ap + kc * 32);
      const int kl = (kc * 32) & 1023;
      a0 = MF(af, *(const bf16x8*)(bp0 + kl), a0);
      a1 = MF(af, *(const bf16x8*)(bp1 + kl), a1);
      a2 = MF(af, *(const bf16x8*)(bp2 + kl), a2);
    }
    const float* gir = gi + (size_t)(t - t0) * 512 * 3072;
    bf16_t* hbw = hb + (size_t)((t + 1) & 1) * 512 * 2048;
#pragma unroll
    for (int q = 0; q < 4; ++q) {
      const size_t rr = (size_t)(rbase + q);
      const float ir = gir[rr * 3072 + myj];
      const float iz = gir[rr * 3072 + 1024 + myj];
      const float in = gir[rr * 3072 + 2048 + myj];
      const float rg_ = fast_sigmoid(ir + a0[q] + bh_r);
      const float zg  = fast_sigmoid(iz + a1[q] + bh_z);
      const float n   = fast_tanh(in + rg_ * (a2[q] + bh_n));
      h[q] = (1.f - zg) * n + zg * h[q];
      const bf16_t hi = f2bf(h[q]);
      hbw[rr * 2048 + myj] = hi;
      hbw[rr * 2048 + 1024 + myj] = f2bf(h[q] - (float)hi);
    }
    grid.sync();
  }

#pragma unroll
  for (int q = 0; q < 4; ++q) {
    const int r = rbase + q;
    Hf[(size_t)r * 1024 + myj] = h[q];
    if (myj < 512) outp[(size_t)r * 512 + myj] = h[q];
    else           outp[262144 + (size_t)r * 512 + (myj - 512)] = h[q];
  }
}

// per-row LayerNorm(+bias) + LeakyReLU(0.1), row width 1024.
template<bool SPLIT>
__global__ __launch_bounds__(256)
void ln_leaky(const float* __restrict__ pre, const float* __restrict__ b,
              const float* __restrict__ g, const float* __restrict__ bet,
              bf16_t* __restrict__ outB, float* __restrict__ zf)
{
  const int row = blockIdx.x;
  const int tid = threadIdx.x;
  const float* p = pre + (size_t)row * 1024;
  float v[4];
  float s = 0.f, s2 = 0.f;
#pragma unroll
  for (int i = 0; i < 4; ++i) {
    const int c = tid + i * 256;
    v[i] = p[c] + b[c];
    s += v[i]; s2 += v[i] * v[i];
  }
#pragma unroll
  for (int o = 32; o; o >>= 1) { s += __shfl_down(s, o); s2 += __shfl_down(s2, o); }
  __shared__ float rs[4], rs2[4];
  if ((tid & 63) == 0) { rs[tid >> 6] = s; rs2[tid >> 6] = s2; }
  __syncthreads();
  s = rs[0] + rs[1] + rs[2] + rs[3];
  s2 = rs2[0] + rs2[1] + rs2[2] + rs2[3];
  const float mu = s * (1.f / 1024.f);
  const float var = s2 * (1.f / 1024.f) - mu * mu;
  const float rstd = rsqrtf(var + 1e-5f);
#pragma unroll
  for (int i = 0; i < 4; ++i) {
    const int c = tid + i * 256;
    float h = (v[i] - mu) * rstd * g[c] + bet[c];
    h = h >= 0.f ? h : 0.1f * h;
    if constexpr (SPLIT) {
      const bf16_t hi = f2bf(h);
      outB[(size_t)row * 2048 + c] = hi;
      outB[(size_t)row * 2048 + 1024 + c] = f2bf(h - (float)hi);
      zf[(size_t)row * 1024 + c] = h;
    } else {
      outB[(size_t)row * 1024 + c] = f2bf(h);
    }
  }
}

__global__ __launch_bounds__(256)
void transpose_bf16(const float* __restrict__ in, bf16_t* __restrict__ out, int R, int C)
{
  __shared__ float t[32][33];
  const int c0 = blockIdx.x * 32, r0 = blockIdx.y * 32;
  const int tx = threadIdx.x & 31, ty = threadIdx.x >> 5;
#pragma unroll
  for (int i = 0; i < 32; i += 8)
    t[ty + i][tx] = in[(size_t)(r0 + ty + i) * C + c0 + tx];
  __syncthreads();
#pragma unroll
  for (int i = 0; i < 32; i += 8)
    out[(size_t)(c0 + ty + i) * R + r0 + tx] = f2bf(t[tx][ty + i]);
}

__global__ __launch_bounds__(256)
void f2b_kernel(const float* __restrict__ in, bf16_t* __restrict__ out, int n)
{
  const int i = blockIdx.x * 256 + threadIdx.x;
  if (i < n) out[i] = f2bf(in[i]);
}

__global__ __launch_bounds__(256)
void dup2_kernel(const bf16_t* __restrict__ in, bf16_t* __restrict__ out, int N, int K)
{
  const int idx = blockIdx.x * 256 + threadIdx.x;
  if (idx >= N * 2 * K) return;
  const int n = idx / (2 * K);
  const int kk = idx - n * 2 * K;
  const int k = kk < K ? kk : kk - K;
  out[idx] = in[(size_t)n * K + k];
}

__global__ void sentinel_kernel(float* out, float code) {
  if (threadIdx.x == 0 && blockIdx.x == 0) out[0] = code;
}

extern "C" void kernel_launch(void* const* d_in, const int* in_sizes, int n_in,
                              void* d_out, int out_size, void* d_ws, size_t ws_size,
                              hipStream_t stream)
{
  const float* xs    = (const float*)d_in[0];
  const float* obs_W = (const float*)d_in[1];
  const float* obs_b = (const float*)d_in[2];
  const float* obs_g = (const float*)d_in[3];
  const float* obs_be= (const float*)d_in[4];
  const float* lat_W = (const float*)d_in[5];
  const float* lat_b = (const float*)d_in[6];
  const float* lat_g = (const float*)d_in[7];
  const float* lat_be= (const float*)d_in[8];
  const float* W0    = (const float*)d_in[9];
  const float* b0    = (const float*)d_in[10];
  const float* W1    = (const float*)d_in[11];
  const float* b1    = (const float*)d_in[12];
  const float* W2    = (const float*)d_in[13];
  const float* b2    = (const float*)d_in[14];
  const float* Wih   = (const float*)d_in[15];
  const float* Whh   = (const float*)d_in[16];
  const float* bih   = (const float*)d_in[17];
  const float* bhh   = (const float*)d_in[18];

  char* ws = (char*)d_ws;
  size_t off = 0;
  auto alloc = [&](size_t bytes) { char* p = ws + off; off += bytes; return p; };

  // ---- static region ----
  bf16_t* OBSWT = (bf16_t*)alloc((size_t)HID * OBS * 2);
  bf16_t* LATWT = (bf16_t*)alloc((size_t)STATEDIM * HID * 2);
  bf16_t* W0T   = (bf16_t*)alloc((size_t)HID * STATEDIM * 2);  // [hid][state], for G GEMMs
  bf16_t* W0T2  = (bf16_t*)alloc((size_t)HID * 2048 * 2);      // K-dup for split-z Z0
  bf16_t* W1T   = (bf16_t*)alloc((size_t)HID * HID * 2);
  bf16_t* W2T   = (bf16_t*)alloc((size_t)STATEDIM * HID * 2);
  bf16_t* WIH2  = (bf16_t*)alloc((size_t)3072 * 2048 * 2);
  bf16_t* WHHB  = (bf16_t*)alloc((size_t)3072 * 1024 * 2);
  float*  Hf    = (float*)alloc((size_t)512 * 1024 * 4);
  bf16_t* HB2   = (bf16_t*)alloc((size_t)2 * 512 * 2048 * 2);
  bf16_t* WIHB  = (bf16_t*)alloc((size_t)3072 * 1024 * 2);     // temp
  bf16_t* XSB   = (bf16_t*)alloc((size_t)ROWS * OBS * 2);      // bf16 input
  const size_t staticEnd = off;

  // ---- chunking: per-row arena
  //   A1f(ZN,4096) A2f(Z,4096) Z0f(4096) H1b(2048) H2b(2048) KB(2048) S2b(4096)
  //   = 22528 B; GIf (12288 B/row) overlaps A1f+A2f+Z0f exactly.
  int nc = -1;
  const int ncs[8] = {1, 2, 4, 8, 16, 32, 64, 128};
  for (int i = 0; i < 8; ++i) {
    const size_t R = (size_t)ROWS / ncs[i];
    if (staticEnd + R * 22528 <= ws_size) { nc = ncs[i]; break; }
  }
  if (nc < 0) {
    sentinel_kernel<<<1, 1, 0, stream>>>((float*)d_out,
                                         -(1000000.0f + (float)(ws_size >> 20)));
    return;
  }
  const int R = ROWS / nc;
  char* arena = ws + staticEnd;
  float*  A1f  = (float*)(arena);                       // pre-LN / ZNf
  float*  A2f  = (float*)(arena + (size_t)R * 4096);    // Zf f32
  float*  Z0f  = (float*)(arena + (size_t)R * 8192);    // z@W0+b0 per step
  bf16_t* H1b  = (bf16_t*)(arena + (size_t)R * 12288);
  bf16_t* H2b  = (bf16_t*)(arena + (size_t)R * 14336);
  bf16_t* KB   = (bf16_t*)(arena + (size_t)R * 16384);  // k bf16 (stage output)
  bf16_t* S2b  = (bf16_t*)(arena + (size_t)R * 18432);  // split z
  float*  GIf  = (float*)(arena);                       // gi f32 overlaps A1..Z0

  auto gemm = [&](int epi, const bf16_t* A, const bf16_t* Wt, const float* bias,
                  int M, int N, int K, float* oF, bf16_t* oB, float kgc = 0.f) {
    dim3 g((M / 128) * (N / 128)), b(256);
    switch (epi) {
      case EPI_F32:  gemm_bt<EPI_F32><<<g, b, 0, stream>>>(A, Wt, bias, M, N, K, oF, oB, A2f, A1f, S2b, Z0f, kgc); break;
      case EPI_GI:   gemm_bt<EPI_GI><<<g, b, 0, stream>>>(A, Wt, bias, M, N, K, oF, oB, A2f, A1f, S2b, Z0f, kgc); break;
      case EPI_TANH: gemm_bt<EPI_TANH><<<g, b, 0, stream>>>(A, Wt, bias, M, N, K, oF, oB, A2f, A1f, S2b, Z0f, kgc); break;
      case EPI_Z0:   gemm_bt<EPI_Z0><<<g, b, 0, stream>>>(A, Wt, bias, M, N, K, oF, oB, A2f, A1f, S2b, Z0f, kgc); break;
      case EPI_KG:   gemm_bt<EPI_KG><<<g, b, 0, stream>>>(A, Wt, bias, M, N, K, oF, oB, A2f, A1f, S2b, Z0f, kgc); break;
      case EPI_K1:   gemm_bt<EPI_K1><<<g, b, 0, stream>>>(A, Wt, bias, M, N, K, oF, oB, A2f, A1f, S2b, Z0f, kgc); break;
      case EPI_K2:   gemm_bt<EPI_K2><<<g, b, 0, stream>>>(A, Wt, bias, M, N, K, oF, oB, A2f, A1f, S2b, Z0f, kgc); break;
      case EPI_K3:   gemm_bt<EPI_K3><<<g, b, 0, stream>>>(A, Wt, bias, M, N, K, oF, oB, A2f, A1f, S2b, Z0f, kgc); break;
      case EPI_K4:   gemm_bt<EPI_K4><<<g, b, 0, stream>>>(A, Wt, bias, M, N, K, oF, oB, A2f, A1f, S2b, Z0f, kgc); break;
    }
  };

  // ---- weight prep ----
  transpose_bf16<<<dim3(HID / 32, OBS / 32), 256, 0, stream>>>(obs_W, OBSWT, OBS, HID);
  transpose_bf16<<<dim3(STATEDIM / 32, HID / 32), 256, 0, stream>>>(lat_W, LATWT, HID, STATEDIM);
  transpose_bf16<<<dim3(HID / 32, STATEDIM / 32), 256, 0, stream>>>(W0, W0T, STATEDIM, HID);
  dup2_kernel<<<(HID * 2048) / 256, 256, 0, stream>>>(W0T, W0T2, HID, 1024);
  transpose_bf16<<<dim3(HID / 32, HID / 32), 256, 0, stream>>>(W1, W1T, HID, HID);
  transpose_bf16<<<dim3(STATEDIM / 32, HID / 32), 256, 0, stream>>>(W2, W2T, HID, STATEDIM);
  f2b_kernel<<<(3072 * 1024) / 256, 256, 0, stream>>>(Wih, WIHB, 3072 * 1024);
  dup2_kernel<<<(3072 * 2048) / 256, 256, 0, stream>>>(WIHB, WIH2, 3072, 1024);
  f2b_kernel<<<(3072 * 1024) / 256, 256, 0, stream>>>(Whh, WHHB, 3072 * 1024);
  f2b_kernel<<<(ROWS * OBS) / 256, 256, 0, stream>>>(xs, XSB, ROWS * OBS);

  hipMemsetAsync(Hf, 0, (size_t)512 * 1024 * 4, stream);
  hipMemsetAsync(HB2, 0, (size_t)2 * 512 * 2048 * 2, stream);
  const int TS = R / BATCHN;

  for (int c = 0; c < nc; ++c) {
    // encoder MLPs
    gemm(EPI_F32, XSB + (size_t)c * R * OBS, OBSWT, nullptr, R, HID, OBS, A1f, nullptr);
    ln_leaky<false><<<R, 256, 0, stream>>>(A1f, obs_b, obs_g, obs_be, H1b, nullptr);
    gemm(EPI_F32, H1b, LATWT, nullptr, R, STATEDIM, HID, A1f, nullptr);
    ln_leaky<true><<<R, 256, 0, stream>>>(A1f, lat_b, lat_g, lat_be, S2b, A2f);

    // RK4: per step: Z0 = z@W0+b0 (split, fuses stage-1 h1), then
    // stages 2-4 via G = k@W0 (plain bf16, K=1024): h1 = tanh(Z0f + c*G).
    for (int step = 0; step < 4; ++step) {
      gemm(EPI_Z0, S2b, W0T2, b0, R, HID, 2048, Z0f, H1b);
      gemm(EPI_TANH, H1b, W1T, b1, R, HID, HID, nullptr, H2b);
      gemm(EPI_K1, H2b, W2T, b2, R, STATEDIM, HID, nullptr, KB);
      for (int stg = 1; stg < 4; ++stg) {
        const float cg = (stg < 3) ? 0.5f * RKDT : RKDT;
        gemm(EPI_KG, KB, W0T, nullptr, R, HID, STATEDIM, nullptr, H1b, cg);
        gemm(EPI_TANH, H1b, W1T, b1, R, HID, HID, nullptr, H2b);
        gemm(EPI_K1 + stg, H2b, W2T, b2, R, STATEDIM, HID, nullptr, KB);
      }
    }

    // gi = z_final @ Wih^T + bih (split-z, f32 out) — overwrites dead A1..Z0
    gemm(EPI_GI, S2b, WIH2, bih, R, 3072, 2048, GIf, nullptr);

    // persistent GRU over this chunk's timesteps
    {
      const float* giArg = GIf;
      const bf16_t* whhArg = WHHB;
      const float* bhhArg = bhh;
      float* hfArg = Hf;
      bf16_t* hbArg = HB2;
      float* outArg = (float*)d_out;
      int tsArg = TS;
      int t0Arg = c * TS;
      void* args[] = { (void*)&giArg, (void*)&whhArg, (void*)&bhhArg,
                       (void*)&hfArg, (void*)&hbArg, (void*)&outArg,
                       (void*)&tsArg, (void*)&t0Arg };
      hipLaunchCooperativeKernel((const void*)gru_persistent,
                                 dim3(256), dim3(512), args, 0, stream);
    }
  }
}